// Round 1
// baseline (64558.496 us; speedup 1.0000x reference)
//
#include <hip/hip_runtime.h>

// TwistorLNN: persistent cooperative kernel, 2 grid barriers per step.
// Matmuls: MFMA 16x16x32 bf16 with bf16x3 (hi/lo split) compensation.
// Everything else fp32.

namespace {

constexpr int Tn = 512, Bn = 256, INn = 256, Hn = 512, On = 64;
constexpr int NBLK = 256, NTHR = 256;
constexpr float DTc = 0.1f, TAU_MINc = 0.01f, TAU_MAXc = 1.0f, DZDT_MAXc = 10.0f, Z_MAXc = 100.0f;

typedef short short8 __attribute__((ext_vector_type(8)));
typedef float f32x4 __attribute__((ext_vector_type(4)));
typedef unsigned short u16;

struct P {
  const float *x, *wtb, *taubias, *outb;
  float *zre, *zim, *dre, *dim;
  u16 *tre_h, *tre_l, *tim_h, *tim_l, *zmod_h, *zmod_l, *zreh, *zrel;
  u16 *xh, *xl;
  u16 *wr_h, *wr_l, *wi_h, *wi_l, *wt_h, *wt_l, *uh, *ul, *oh, *ol;
  float *bias_re, *bias_im, *acc;
  int *bar;
  float *out;
};

__device__ __forceinline__ u16 f2bf(float f) {
  union { float f; unsigned u; } v; v.f = f;
  unsigned r = v.u + 0x7fffu + ((v.u >> 16) & 1u);
  return (u16)(r >> 16);
}
__device__ __forceinline__ float bf2f(u16 h) {
  union { unsigned u; float f; } v; v.u = ((unsigned)h) << 16;
  return v.f;
}
__device__ __forceinline__ void split_store(float v, u16* hi, u16* lo) {
  u16 h = f2bf(v); *hi = h; *lo = f2bf(v - bf2f(h));
}

// ---------------- prep: gate + hi/lo split weights, fold biases ----------------
__global__ void prep_k(const float* Wr, const float* mr, const float* Wi, const float* mi,
                       const float* Wt, const float* U, const float* Ow,
                       const float* Wrb, const float* Ub, const float* brl,
                       const float* Wib, const float* bim, P p) {
  int i = blockIdx.x * NTHR + threadIdx.x;
  if (i < Hn * Hn) {
    float g = 1.f / (1.f + expf(-mr[i]));
    split_store(Wr[i] * g, &p.wr_h[i], &p.wr_l[i]);
    g = 1.f / (1.f + expf(-mi[i]));
    split_store(Wi[i] * g, &p.wi_h[i], &p.wi_l[i]);
    split_store(Wt[i], &p.wt_h[i], &p.wt_l[i]);
  }
  if (i < Hn * INn) split_store(U[i], &p.uh[i], &p.ul[i]);
  if (i < On * Hn)  split_store(Ow[i], &p.oh[i], &p.ol[i]);
  if (i < Hn) {
    p.bias_re[i] = Wrb[i] + Ub[i] + brl[i];
    p.bias_im[i] = Wib[i] + Ub[i] + bim[i];
  }
}

// ---------------- init: zero state, publish Z_0 activations, x[0] split ----------------
__global__ void init_k(P p) {
  int i = blockIdx.x * NTHR + threadIdx.x;
  if (i < Bn * Hn) {
    p.zre[i] = 0.f; p.zim[i] = 0.f;
    p.tre_h[i] = 0; p.tre_l[i] = 0; p.tim_h[i] = 0; p.tim_l[i] = 0;
    p.zreh[i] = 0; p.zrel[i] = 0;
    split_store(1e-6f, &p.zmod_h[i], &p.zmod_l[i]);  // sqrt(0+0+1e-12)
  }
  if (i < Bn * INn) split_store(p.x[i], &p.xh[i], &p.xl[i]);
  if (i < Tn) p.acc[i] = 0.f;
  if (i < 2) p.bar[i] = 0;
}

// ---------------- grid barrier: atomic arrive + generation spin ----------------
__device__ __forceinline__ void gbar(int* bar) {
  __syncthreads();
  if (threadIdx.x == 0) {
    __threadfence();  // release all this block's stores (agent scope, cross-XCD)
    int* cnt = bar; int* gen = bar + 1;
    int g = __hip_atomic_load(gen, __ATOMIC_RELAXED, __HIP_MEMORY_SCOPE_AGENT);
    int a = __hip_atomic_fetch_add(cnt, 1, __ATOMIC_ACQ_REL, __HIP_MEMORY_SCOPE_AGENT);
    if (a == NBLK - 1) {
      __hip_atomic_store(cnt, 0, __ATOMIC_RELAXED, __HIP_MEMORY_SCOPE_AGENT);
      __hip_atomic_fetch_add(gen, 1, __ATOMIC_RELEASE, __HIP_MEMORY_SCOPE_AGENT);
    } else {
      while (__hip_atomic_load(gen, __ATOMIC_ACQUIRE, __HIP_MEMORY_SCOPE_AGENT) == g)
        __builtin_amdgcn_s_sleep(2);
    }
    __threadfence();  // acquire side
  }
  __syncthreads();
}

// ---------------- one 16x16 tile, K-loop, bf16x3 (AhBh + AhBl + AlBh) ----------------
// A[m][k]: m = lane&15, k-octet = (lane>>4)*8. B'[n][k] (row-major N x K): n = lane&15.
// D[row = (lane>>4)*4 + r][col = lane&15].
template <int K>
__device__ __forceinline__ f32x4 mm_job(const u16* ah, const u16* al,
                                        const u16* bh, const u16* bl,
                                        int arow0, int brow0, int lda, int ldb,
                                        int m, int q) {
  f32x4 acc = {0.f, 0.f, 0.f, 0.f};
  const u16* ap  = ah + (size_t)(arow0 + m) * lda + q * 8;
  const u16* alp = al + (size_t)(arow0 + m) * lda + q * 8;
  const u16* bp  = bh + (size_t)(brow0 + m) * ldb + q * 8;
  const u16* blp = bl + (size_t)(brow0 + m) * ldb + q * 8;
#pragma unroll 4
  for (int k0 = 0; k0 < K; k0 += 32) {
    short8 Ah = *(const short8*)(ap + k0);
    short8 Al = *(const short8*)(alp + k0);
    short8 Bh = *(const short8*)(bp + k0);
    short8 Bl = *(const short8*)(blp + k0);
    acc = __builtin_amdgcn_mfma_f32_16x16x32_bf16(Ah, Bh, acc, 0, 0, 0);
    acc = __builtin_amdgcn_mfma_f32_16x16x32_bf16(Ah, Bl, acc, 0, 0, 0);
    acc = __builtin_amdgcn_mfma_f32_16x16x32_bf16(Al, Bh, acc, 0, 0, 0);
  }
  return acc;
}

__device__ __forceinline__ void yjob(const P& p, int rowbase, int cg, int ty, int m, int q) {
  f32x4 a = mm_job<Hn>(p.zreh, p.zrel, p.oh, p.ol, rowbase, cg * 16, Hn, Hn, m, q);
  int o = cg * 16 + m;
#pragma unroll
  for (int r = 0; r < 4; ++r) {
    int b = rowbase + q * 4 + r;
    p.out[((size_t)ty * Bn + b) * On + o] = a[r] + p.outb[o];
  }
}

// ---------------- persistent loop kernel ----------------
__global__ void __launch_bounds__(NTHR) twistor_k(P p) {
  const int bid = blockIdx.x, tid = threadIdx.x;
  const int rg = bid >> 5, cg = bid & 31;           // 8 row-groups x 32 col-groups
  const int wave = tid >> 6, lane = tid & 63, m = lane & 15, q = lane >> 4;
  const int row0 = rg * 32, col0 = cg * 16;
  __shared__ float res[4][32][16];  // re, im, tau, ux partial results
  __shared__ float wsum[4];
  __shared__ float sscale;

  for (int t = 0; t < Tn; ++t) {
    // ===== phase A: matmuls from Z_t, then dz/tau/d + norm partial =====
    if (wave == 0) {
      f32x4 a0 = mm_job<Hn>(p.tre_h, p.tre_l, p.wr_h, p.wr_l, row0,      col0, Hn, Hn, m, q);
      f32x4 a1 = mm_job<Hn>(p.tre_h, p.tre_l, p.wr_h, p.wr_l, row0 + 16, col0, Hn, Hn, m, q);
#pragma unroll
      for (int r = 0; r < 4; ++r) { res[0][q*4+r][m] = a0[r]; res[0][16+q*4+r][m] = a1[r]; }
    } else if (wave == 1) {
      f32x4 a0 = mm_job<Hn>(p.tim_h, p.tim_l, p.wi_h, p.wi_l, row0,      col0, Hn, Hn, m, q);
      f32x4 a1 = mm_job<Hn>(p.tim_h, p.tim_l, p.wi_h, p.wi_l, row0 + 16, col0, Hn, Hn, m, q);
#pragma unroll
      for (int r = 0; r < 4; ++r) { res[1][q*4+r][m] = a0[r]; res[1][16+q*4+r][m] = a1[r]; }
    } else if (wave == 2) {
      f32x4 a0 = mm_job<Hn>(p.zmod_h, p.zmod_l, p.wt_h, p.wt_l, row0,      col0, Hn, Hn, m, q);
      f32x4 a1 = mm_job<Hn>(p.zmod_h, p.zmod_l, p.wt_h, p.wt_l, row0 + 16, col0, Hn, Hn, m, q);
#pragma unroll
      for (int r = 0; r < 4; ++r) { res[2][q*4+r][m] = a0[r]; res[2][16+q*4+r][m] = a1[r]; }
      if (cg < 4 && t > 0) yjob(p, row0 + 16, cg, t - 1, m, q);   // y_{t-1}, upper 16 rows
    } else {
      f32x4 a0 = mm_job<INn>(p.xh, p.xl, p.uh, p.ul, row0,      col0, INn, INn, m, q);
      f32x4 a1 = mm_job<INn>(p.xh, p.xl, p.uh, p.ul, row0 + 16, col0, INn, INn, m, q);
#pragma unroll
      for (int r = 0; r < 4; ++r) { res[3][q*4+r][m] = a0[r]; res[3][16+q*4+r][m] = a1[r]; }
      if (cg < 4 && t > 0) yjob(p, row0, cg, t - 1, m, q);        // y_{t-1}, lower 16 rows
    }
    __syncthreads();

    float pn = 0.f;
#pragma unroll
    for (int u = 0; u < 2; ++u) {
      int e = tid + u * NTHR;
      int r = e >> 4, c = e & 15;
      int b = row0 + r, j = col0 + c;
      size_t idx = (size_t)b * Hn + j;
      float zr = p.zre[idx], zi = p.zim[idx];
      float ux = res[3][r][c];
      float dzre = -zr + res[0][r][c] + ux + p.bias_re[j];
      float dzim = -zi + res[1][r][c] + ux + p.bias_im[j];
      float tau = 1.f / (1.f + expf(-(res[2][r][c] + p.wtb[j])));
      tau = fminf(fmaxf(tau + p.taubias[j], TAU_MINc), TAU_MAXc) + 1e-6f;
      float dr = fminf(fmaxf(dzre / tau, -DZDT_MAXc), DZDT_MAXc);
      float di = fminf(fmaxf(dzim / tau, -DZDT_MAXc), DZDT_MAXc);
      p.dre[idx] = dr; p.dim[idx] = di;
      pn += sqrtf(dr * dr + di * di + 1e-12f);
    }
#pragma unroll
    for (int off = 32; off > 0; off >>= 1) pn += __shfl_down(pn, off, 64);
    if (lane == 0) wsum[wave] = pn;
    __syncthreads();
    if (tid == 0) atomicAdd(&p.acc[t], wsum[0] + wsum[1] + wsum[2] + wsum[3]);
    gbar(p.bar);

    // ===== phase B: scale, state update, publish Z_{t+1} activations =====
    if (tid == 0) {
      float s = __hip_atomic_load(&p.acc[t], __ATOMIC_ACQUIRE, __HIP_MEMORY_SCOPE_AGENT);
      float mean = s * (1.f / (float)(Bn * Hn));
      sscale = (mean > 0.5f * DZDT_MAXc) ? (0.5f * DZDT_MAXc) / (mean + 1e-6f) : 1.f;
    }
    __syncthreads();
    float scale = sscale;
    size_t base = (size_t)bid * 512 + (size_t)tid * 2;   // block bid owns batch row bid
#pragma unroll
    for (int u = 0; u < 2; ++u) {
      size_t idx = base + u;
      float zr = p.zre[idx] + DTc * scale * p.dre[idx];
      zr = fminf(fmaxf(zr, -Z_MAXc), Z_MAXc);
      float zi = p.zim[idx] + DTc * scale * p.dim[idx];
      zi = fminf(fmaxf(zi, -Z_MAXc), Z_MAXc);
      p.zre[idx] = zr; p.zim[idx] = zi;
      float tr = tanhf(zr), ti = tanhf(zi);
      split_store(tr, &p.tre_h[idx], &p.tre_l[idx]);
      split_store(ti, &p.tim_h[idx], &p.tim_l[idx]);
      split_store(sqrtf(zr * zr + zi * zi + 1e-12f), &p.zmod_h[idx], &p.zmod_l[idx]);
      split_store(zr, &p.zreh[idx], &p.zrel[idx]);
    }
    if (t + 1 < Tn) {
      int xi = bid * NTHR + tid;
      split_store(p.x[(size_t)(t + 1) * (Bn * INn) + xi], &p.xh[xi], &p.xl[xi]);
    }
    gbar(p.bar);
  }

  // final y_{T-1} from Z_T
  if (cg < 4) {
    if (wave == 2)      yjob(p, row0 + 16, cg, Tn - 1, m, q);
    else if (wave == 3) yjob(p, row0,      cg, Tn - 1, m, q);
  }
}

}  // namespace

extern "C" void kernel_launch(void* const* d_in, const int* in_sizes, int n_in,
                              void* d_out, int out_size, void* d_ws, size_t ws_size,
                              hipStream_t stream) {
  (void)in_sizes; (void)n_in; (void)out_size; (void)ws_size;
  char* w = (char*)d_ws;
  auto alloc = [&](size_t bytes) -> char* {
    char* r = w; w += (bytes + 255) & ~(size_t)255; return r;
  };

  P p;
  p.x       = (const float*)d_in[0];
  const float* Wr  = (const float*)d_in[1];
  const float* Wrb = (const float*)d_in[2];
  const float* Wi  = (const float*)d_in[3];
  const float* Wib = (const float*)d_in[4];
  const float* U   = (const float*)d_in[5];
  const float* Ub  = (const float*)d_in[6];
  const float* Wt  = (const float*)d_in[7];
  p.wtb     = (const float*)d_in[8];
  const float* mr  = (const float*)d_in[9];
  const float* mi  = (const float*)d_in[10];
  p.taubias = (const float*)d_in[11];
  const float* brl = (const float*)d_in[12];
  const float* bim = (const float*)d_in[13];
  const float* Ow  = (const float*)d_in[14];
  p.outb    = (const float*)d_in[15];

  p.zre = (float*)alloc(Bn * Hn * 4);  p.zim = (float*)alloc(Bn * Hn * 4);
  p.dre = (float*)alloc(Bn * Hn * 4);  p.dim = (float*)alloc(Bn * Hn * 4);
  p.tre_h = (u16*)alloc(Bn * Hn * 2);  p.tre_l = (u16*)alloc(Bn * Hn * 2);
  p.tim_h = (u16*)alloc(Bn * Hn * 2);  p.tim_l = (u16*)alloc(Bn * Hn * 2);
  p.zmod_h = (u16*)alloc(Bn * Hn * 2); p.zmod_l = (u16*)alloc(Bn * Hn * 2);
  p.zreh = (u16*)alloc(Bn * Hn * 2);   p.zrel = (u16*)alloc(Bn * Hn * 2);
  p.xh = (u16*)alloc(Bn * INn * 2);    p.xl = (u16*)alloc(Bn * INn * 2);
  p.wr_h = (u16*)alloc(Hn * Hn * 2);   p.wr_l = (u16*)alloc(Hn * Hn * 2);
  p.wi_h = (u16*)alloc(Hn * Hn * 2);   p.wi_l = (u16*)alloc(Hn * Hn * 2);
  p.wt_h = (u16*)alloc(Hn * Hn * 2);   p.wt_l = (u16*)alloc(Hn * Hn * 2);
  p.uh = (u16*)alloc(Hn * INn * 2);    p.ul = (u16*)alloc(Hn * INn * 2);
  p.oh = (u16*)alloc(On * Hn * 2);     p.ol = (u16*)alloc(On * Hn * 2);
  p.bias_re = (float*)alloc(Hn * 4);   p.bias_im = (float*)alloc(Hn * 4);
  p.acc = (float*)alloc(Tn * 4);
  p.bar = (int*)alloc(256);
  p.out = (float*)d_out;

  prep_k<<<(Hn * Hn + NTHR - 1) / NTHR, NTHR, 0, stream>>>(Wr, mr, Wi, mi, Wt, U, Ow,
                                                           Wrb, Ub, brl, Wib, bim, p);
  init_k<<<(Bn * Hn + NTHR - 1) / NTHR, NTHR, 0, stream>>>(p);

  void* args[] = { &p };
  hipLaunchCooperativeKernel((void*)twistor_k, dim3(NBLK), dim3(NTHR), args, 0, stream);
}

// Round 3
// 17223.320 us; speedup vs baseline: 3.7483x; 3.7483x over previous
//
#include <hip/hip_runtime.h>

// TwistorLNN persistent cooperative kernel, round 3 (= round-2 design, compile fix).
// - All weight B-fragments staged in LDS once (150 KB dynamic LDS, 1 block/CU):
//   immune to the L2 invalidations the grid barrier fences perform.
// - z and d state live in registers of the owning block (block owns 32 rows x 16 cols);
//   only activations (tanh, |z|, z hi/lo bf16 splits) cross blocks each step.
// - Barrier spins on RELAXED atomic (no buffer_inv per spin), one acquire fence on exit.
// - MFMA 16x16x32 bf16, bf16x3 compensation (AhBh + AhBl + AlBh).

namespace {

constexpr int Tn = 512, Bn = 256, INn = 256, Hn = 512, On = 64;
constexpr int NBLK = 256, NTHR = 256;
constexpr float DTc = 0.1f, TAU_MINc = 0.01f, TAU_MAXc = 1.0f, DZDT_MAXc = 10.0f, Z_MAXc = 100.0f;

// padded K-strides (u16 units) for conflict-free ds_read_b128
constexpr int LDH = 520;   // K=512 tiles
constexpr int LDI = 264;   // K=256 tiles

// dynamic-LDS layout, u16 offsets (all byte offsets 16B-aligned)
constexpr int O_WRH = 0,     O_WRL = 8320,  O_WIH = 16640, O_WIL = 24960;
constexpr int O_WTH = 33280, O_WTL = 41600;
constexpr int O_UH  = 49920, O_UL  = 54144;
constexpr int O_OH  = 58368, O_OL  = 66688;
constexpr int DYN_BYTES = 75008 * 2;  // 150016

typedef short short8 __attribute__((ext_vector_type(8)));
typedef float f32x4 __attribute__((ext_vector_type(4)));
typedef unsigned short u16;
typedef unsigned int u32;

#define MFMA(a, b, c) __builtin_amdgcn_mfma_f32_16x16x32_bf16((a), (b), (c), 0, 0, 0)

struct P {
  const float *x, *wtb, *taubias, *outb;
  u16 *tre_h, *tre_l, *tim_h, *tim_l, *zmod_h, *zmod_l, *zreh, *zrel;
  u16 *xh, *xl;
  u16 *wr_h, *wr_l, *wi_h, *wi_l, *wt_h, *wt_l, *uh, *ul, *oh, *ol;
  float *bias_re, *bias_im, *acc;
  int *bar;
  float *out;
};

__device__ __forceinline__ u16 f2bf(float f) {
  union { float f; unsigned u; } v; v.f = f;
  unsigned r = v.u + 0x7fffu + ((v.u >> 16) & 1u);
  return (u16)(r >> 16);
}
__device__ __forceinline__ float bf2f(u16 h) {
  union { unsigned u; float f; } v; v.u = ((unsigned)h) << 16;
  return v.f;
}
__device__ __forceinline__ void split_store(float v, u16* hi, u16* lo) {
  u16 h = f2bf(v); *hi = h; *lo = f2bf(v - bf2f(h));
}
__device__ __forceinline__ void split2(float v, u16& h, u16& l) {
  h = f2bf(v); l = f2bf(v - bf2f(h));
}
__device__ __forceinline__ u32 pk(u16 a, u16 b) { return (u32)a | ((u32)b << 16); }

// ---------------- prep: gate + hi/lo split weights, fold biases ----------------
__global__ void prep_k(const float* Wr, const float* mr, const float* Wi, const float* mi,
                       const float* Wt, const float* U, const float* Ow,
                       const float* Wrb, const float* Ub, const float* brl,
                       const float* Wib, const float* bim, P p) {
  int i = blockIdx.x * NTHR + threadIdx.x;
  if (i < Hn * Hn) {
    float g = 1.f / (1.f + expf(-mr[i]));
    split_store(Wr[i] * g, &p.wr_h[i], &p.wr_l[i]);
    g = 1.f / (1.f + expf(-mi[i]));
    split_store(Wi[i] * g, &p.wi_h[i], &p.wi_l[i]);
    split_store(Wt[i], &p.wt_h[i], &p.wt_l[i]);
  }
  if (i < Hn * INn) split_store(U[i], &p.uh[i], &p.ul[i]);
  if (i < On * Hn)  split_store(Ow[i], &p.oh[i], &p.ol[i]);
  if (i < Hn) {
    p.bias_re[i] = Wrb[i] + Ub[i] + brl[i];
    p.bias_im[i] = Wib[i] + Ub[i] + bim[i];
  }
}

// ---------------- init: publish Z_0 activations, x[0] split, zero acc/bar ----------------
__global__ void init_k(P p) {
  int i = blockIdx.x * NTHR + threadIdx.x;
  if (i < Bn * Hn) {
    p.tre_h[i] = 0; p.tre_l[i] = 0; p.tim_h[i] = 0; p.tim_l[i] = 0;
    p.zreh[i] = 0; p.zrel[i] = 0;
    split_store(1e-6f, &p.zmod_h[i], &p.zmod_l[i]);
  }
  if (i < Bn * INn) split_store(p.x[i], &p.xh[i], &p.xl[i]);
  if (i < Tn) p.acc[i] = 0.f;
  if (i < 64) p.bar[i] = 0;
}

// ---------------- grid barrier: RELAXED spin, one acquire fence on exit ----------------
__device__ __forceinline__ void gbar(int* bar) {
  __syncthreads();
  if (threadIdx.x == 0) {
    __threadfence();  // release: write back this XCD's dirty lines
    int* cnt = bar; int* gen = bar + 32;
    int g = __hip_atomic_load(gen, __ATOMIC_RELAXED, __HIP_MEMORY_SCOPE_AGENT);
    int a = __hip_atomic_fetch_add(cnt, 1, __ATOMIC_RELAXED, __HIP_MEMORY_SCOPE_AGENT);
    if (a == NBLK - 1) {
      __hip_atomic_store(cnt, 0, __ATOMIC_RELAXED, __HIP_MEMORY_SCOPE_AGENT);
      __hip_atomic_store(gen, g + 1, __ATOMIC_RELEASE, __HIP_MEMORY_SCOPE_AGENT);
    } else {
      while (__hip_atomic_load(gen, __ATOMIC_RELAXED, __HIP_MEMORY_SCOPE_AGENT) == g)
        __builtin_amdgcn_s_sleep(2);
    }
    __threadfence();  // acquire: invalidate so fresh cross-XCD data is visible
  }
  __syncthreads();
}

// ---------------- stage one 16-row weight tile into LDS ----------------
template <int K, int LD>
__device__ __forceinline__ void stage(const u16* __restrict__ src, u16* dst, int grow0, int tid) {
  constexpr int CH = K / 8;
#pragma unroll
  for (int i = tid; i < 16 * CH; i += NTHR) {
    int n = i / CH, kk = (i % CH) * 8;
    *(short8*)(dst + n * LD + kk) = *(const short8*)(src + (size_t)(grow0 + n) * K + kk);
  }
}

// ---------------- two 16x16 tiles sharing one B-tile; A global, B LDS ----------------
template <int K, int LDB>
__device__ __forceinline__ void mm2(const u16* __restrict__ ah, const u16* __restrict__ al,
                                    const u16* bh, const u16* bl,
                                    int arow0, int lda, int m, int q,
                                    f32x4& acc0, f32x4& acc1) {
  const u16* a0h = ah + (size_t)(arow0 + m) * lda + q * 8;
  const u16* a0l = al + (size_t)(arow0 + m) * lda + q * 8;
  const u16* a1h = a0h + 16 * lda;
  const u16* a1l = a0l + 16 * lda;
  const u16* bp  = bh + m * LDB + q * 8;
  const u16* blp = bl + m * LDB + q * 8;
#pragma unroll 8
  for (int k0 = 0; k0 < K; k0 += 32) {
    short8 Bh = *(const short8*)(bp + k0);
    short8 Bl = *(const short8*)(blp + k0);
    short8 A0h = *(const short8*)(a0h + k0);
    short8 A0l = *(const short8*)(a0l + k0);
    short8 A1h = *(const short8*)(a1h + k0);
    short8 A1l = *(const short8*)(a1l + k0);
    acc0 = MFMA(A0h, Bh, acc0); acc0 = MFMA(A0h, Bl, acc0); acc0 = MFMA(A0l, Bh, acc0);
    acc1 = MFMA(A1h, Bh, acc1); acc1 = MFMA(A1h, Bl, acc1); acc1 = MFMA(A1l, Bh, acc1);
  }
}

// ---------------- one y-tile: zre (global) x out_w (LDS) ----------------
__device__ __forceinline__ void yjob(const P& p, const u16* bh, const u16* bl,
                                     int rowbase, int ocol0, int ty, int m, int q) {
  f32x4 acc = {0.f, 0.f, 0.f, 0.f};
  const u16* ah  = p.zreh + (size_t)(rowbase + m) * Hn + q * 8;
  const u16* al  = p.zrel + (size_t)(rowbase + m) * Hn + q * 8;
  const u16* bp  = bh + m * LDH + q * 8;
  const u16* blp = bl + m * LDH + q * 8;
#pragma unroll 8
  for (int k0 = 0; k0 < Hn; k0 += 32) {
    short8 Bh = *(const short8*)(bp + k0);
    short8 Bl = *(const short8*)(blp + k0);
    short8 Ah = *(const short8*)(ah + k0);
    short8 Al = *(const short8*)(al + k0);
    acc = MFMA(Ah, Bh, acc); acc = MFMA(Ah, Bl, acc); acc = MFMA(Al, Bh, acc);
  }
  int o = ocol0 + m;
  float ob = p.outb[o];
#pragma unroll
  for (int i = 0; i < 4; ++i)
    p.out[((size_t)ty * Bn + rowbase + q * 4 + i) * On + o] = acc[i] + ob;
}

// ---------------- persistent loop kernel ----------------
__global__ void __launch_bounds__(NTHR, 1) twistor_k(P p) {
  extern __shared__ __align__(16) u16 smem[];
  __shared__ float res[4][32][16];   // re, im, tau, ux results for the block's 32x16 tile
  __shared__ float sb[4][16];        // bias_re, bias_im, wtb, taubias tiles
  __shared__ float wsum[4];
  __shared__ float sscale;

  const int bid = blockIdx.x, tid = threadIdx.x;
  const int rg = bid & 7, cg = bid >> 3;        // rg on same XCD (bid%8 heuristic)
  const int wave = tid >> 6, lane = tid & 63, m = lane & 15, q = lane >> 4;
  const int row0 = rg * 32, col0 = cg * 16;
  const bool yblk = (cg >= 8 && cg < 16);
  const int yk = cg - 8;
  const int yrowbase = row0 + 16 * (yk & 1);
  const int yocol = (yk >> 1) * 16;

  // one-time: stage this block's weight tiles into LDS
  stage<Hn, LDH>(p.wr_h, smem + O_WRH, col0, tid);
  stage<Hn, LDH>(p.wr_l, smem + O_WRL, col0, tid);
  stage<Hn, LDH>(p.wi_h, smem + O_WIH, col0, tid);
  stage<Hn, LDH>(p.wi_l, smem + O_WIL, col0, tid);
  stage<Hn, LDH>(p.wt_h, smem + O_WTH, col0, tid);
  stage<Hn, LDH>(p.wt_l, smem + O_WTL, col0, tid);
  stage<INn, LDI>(p.uh, smem + O_UH, col0, tid);
  stage<INn, LDI>(p.ul, smem + O_UL, col0, tid);
  int orow0 = yblk ? yocol : 0;
  stage<Hn, LDH>(p.oh, smem + O_OH, orow0, tid);
  stage<Hn, LDH>(p.ol, smem + O_OL, orow0, tid);
  if (tid < 16) {
    sb[0][tid] = p.bias_re[col0 + tid];
    sb[1][tid] = p.bias_im[col0 + tid];
    sb[2][tid] = p.wtb[col0 + tid];
    sb[3][tid] = p.taubias[col0 + tid];
  }
  __syncthreads();

  // this thread owns elements (row0 + r, col0 + c0) and (row0 + r, col0 + c0 + 1)
  const int r = tid >> 3, c0 = (tid & 7) * 2;
  float zrA[2] = {0.f, 0.f}, ziA[2] = {0.f, 0.f};

  for (int t = 0; t < Tn; ++t) {
    // ===== phase A: 4 matmul jobs (one per wave) from published Z_t activations =====
    f32x4 a0 = {0.f,0.f,0.f,0.f}, a1 = {0.f,0.f,0.f,0.f};
    if (wave == 0) {
      mm2<Hn, LDH>(p.tre_h, p.tre_l, smem + O_WRH, smem + O_WRL, row0, Hn, m, q, a0, a1);
    } else if (wave == 1) {
      mm2<Hn, LDH>(p.tim_h, p.tim_l, smem + O_WIH, smem + O_WIL, row0, Hn, m, q, a0, a1);
    } else if (wave == 2) {
      mm2<Hn, LDH>(p.zmod_h, p.zmod_l, smem + O_WTH, smem + O_WTL, row0, Hn, m, q, a0, a1);
    } else {
      mm2<INn, LDI>(p.xh, p.xl, smem + O_UH, smem + O_UL, row0, INn, m, q, a0, a1);
      if (yblk && t > 0) yjob(p, smem + O_OH, smem + O_OL, yrowbase, yocol, t - 1, m, q);
    }
#pragma unroll
    for (int i = 0; i < 4; ++i) {
      res[wave][q * 4 + i][m] = a0[i];
      res[wave][16 + q * 4 + i][m] = a1[i];
    }
    __syncthreads();

    // epilogue: dz, tau, d for own 2 elements (all LDS/regs)
    float drs[2], dis[2];
    float pn = 0.f;
#pragma unroll
    for (int u = 0; u < 2; ++u) {
      int c = c0 + u;
      float ux = res[3][r][c];
      float dzre = -zrA[u] + res[0][r][c] + ux + sb[0][c];
      float dzim = -ziA[u] + res[1][r][c] + ux + sb[1][c];
      float tau = 1.f / (1.f + expf(-(res[2][r][c] + sb[2][c])));
      tau = fminf(fmaxf(tau + sb[3][c], TAU_MINc), TAU_MAXc) + 1e-6f;
      float dr = fminf(fmaxf(dzre / tau, -DZDT_MAXc), DZDT_MAXc);
      float di = fminf(fmaxf(dzim / tau, -DZDT_MAXc), DZDT_MAXc);
      drs[u] = dr; dis[u] = di;
      pn += sqrtf(dr * dr + di * di + 1e-12f);
    }
#pragma unroll
    for (int off = 32; off > 0; off >>= 1) pn += __shfl_down(pn, off, 64);
    if (lane == 0) wsum[wave] = pn;
    __syncthreads();
    if (tid == 0) {
      float s = wsum[0] + wsum[1] + wsum[2] + wsum[3];
      __hip_atomic_fetch_add(&p.acc[t], s, __ATOMIC_RELAXED, __HIP_MEMORY_SCOPE_AGENT);
    }
    gbar(p.bar);

    // ===== phase B: scale, own z update (regs), publish Z_{t+1} activations =====
    if (tid == 0) {
      float s = __hip_atomic_load(&p.acc[t], __ATOMIC_RELAXED, __HIP_MEMORY_SCOPE_AGENT);
      float mean = s * (1.f / (float)(Bn * Hn));
      sscale = (mean > 0.5f * DZDT_MAXc) ? (0.5f * DZDT_MAXc) / (mean + 1e-6f) : 1.f;
    }
    __syncthreads();
    float scale = sscale;

    u16 h0, l0, h1, l1;
    size_t idx0 = (size_t)(row0 + r) * Hn + col0 + c0;
#pragma unroll
    for (int u = 0; u < 2; ++u) {
      zrA[u] = fminf(fmaxf(zrA[u] + DTc * scale * drs[u], -Z_MAXc), Z_MAXc);
      ziA[u] = fminf(fmaxf(ziA[u] + DTc * scale * dis[u], -Z_MAXc), Z_MAXc);
    }
    split2(tanhf(zrA[0]), h0, l0); split2(tanhf(zrA[1]), h1, l1);
    *(u32*)(p.tre_h + idx0) = pk(h0, h1); *(u32*)(p.tre_l + idx0) = pk(l0, l1);
    split2(tanhf(ziA[0]), h0, l0); split2(tanhf(ziA[1]), h1, l1);
    *(u32*)(p.tim_h + idx0) = pk(h0, h1); *(u32*)(p.tim_l + idx0) = pk(l0, l1);
    split2(sqrtf(zrA[0]*zrA[0] + ziA[0]*ziA[0] + 1e-12f), h0, l0);
    split2(sqrtf(zrA[1]*zrA[1] + ziA[1]*ziA[1] + 1e-12f), h1, l1);
    *(u32*)(p.zmod_h + idx0) = pk(h0, h1); *(u32*)(p.zmod_l + idx0) = pk(l0, l1);
    split2(zrA[0], h0, l0); split2(zrA[1], h1, l1);
    *(u32*)(p.zreh + idx0) = pk(h0, h1); *(u32*)(p.zrel + idx0) = pk(l0, l1);

    if (t + 1 < Tn) {
      int xi = bid * NTHR + tid;
      split_store(p.x[(size_t)(t + 1) * (Bn * INn) + xi], &p.xh[xi], &p.xl[xi]);
    }
    gbar(p.bar);
  }

  // final y_{T-1} from Z_T
  if (yblk && wave == 3) yjob(p, smem + O_OH, smem + O_OL, yrowbase, yocol, Tn - 1, m, q);
}

}  // namespace

extern "C" void kernel_launch(void* const* d_in, const int* in_sizes, int n_in,
                              void* d_out, int out_size, void* d_ws, size_t ws_size,
                              hipStream_t stream) {
  (void)in_sizes; (void)n_in; (void)out_size; (void)ws_size;
  char* w = (char*)d_ws;
  auto alloc = [&](size_t bytes) -> char* {
    char* r = w; w += (bytes + 255) & ~(size_t)255; return r;
  };

  P p;
  p.x       = (const float*)d_in[0];
  const float* Wr  = (const float*)d_in[1];
  const float* Wrb = (const float*)d_in[2];
  const float* Wi  = (const float*)d_in[3];
  const float* Wib = (const float*)d_in[4];
  const float* U   = (const float*)d_in[5];
  const float* Ub  = (const float*)d_in[6];
  const float* Wt  = (const float*)d_in[7];
  p.wtb     = (const float*)d_in[8];
  const float* mr  = (const float*)d_in[9];
  const float* mi  = (const float*)d_in[10];
  p.taubias = (const float*)d_in[11];
  const float* brl = (const float*)d_in[12];
  const float* bim = (const float*)d_in[13];
  const float* Ow  = (const float*)d_in[14];
  p.outb    = (const float*)d_in[15];

  p.tre_h = (u16*)alloc(Bn * Hn * 2);  p.tre_l = (u16*)alloc(Bn * Hn * 2);
  p.tim_h = (u16*)alloc(Bn * Hn * 2);  p.tim_l = (u16*)alloc(Bn * Hn * 2);
  p.zmod_h = (u16*)alloc(Bn * Hn * 2); p.zmod_l = (u16*)alloc(Bn * Hn * 2);
  p.zreh = (u16*)alloc(Bn * Hn * 2);   p.zrel = (u16*)alloc(Bn * Hn * 2);
  p.xh = (u16*)alloc(Bn * INn * 2);    p.xl = (u16*)alloc(Bn * INn * 2);
  p.wr_h = (u16*)alloc(Hn * Hn * 2);   p.wr_l = (u16*)alloc(Hn * Hn * 2);
  p.wi_h = (u16*)alloc(Hn * Hn * 2);   p.wi_l = (u16*)alloc(Hn * Hn * 2);
  p.wt_h = (u16*)alloc(Hn * Hn * 2);   p.wt_l = (u16*)alloc(Hn * Hn * 2);
  p.uh = (u16*)alloc(Hn * INn * 2);    p.ul = (u16*)alloc(Hn * INn * 2);
  p.oh = (u16*)alloc(On * Hn * 2);     p.ol = (u16*)alloc(On * Hn * 2);
  p.bias_re = (float*)alloc(Hn * 4);   p.bias_im = (float*)alloc(Hn * 4);
  p.acc = (float*)alloc(Tn * 4);
  p.bar = (int*)alloc(256);
  p.out = (float*)d_out;

  prep_k<<<(Hn * Hn + NTHR - 1) / NTHR, NTHR, 0, stream>>>(Wr, mr, Wi, mi, Wt, U, Ow,
                                                           Wrb, Ub, brl, Wib, bim, p);
  init_k<<<(Bn * Hn + NTHR - 1) / NTHR, NTHR, 0, stream>>>(p);

  (void)hipFuncSetAttribute((const void*)twistor_k,
                            hipFuncAttributeMaxDynamicSharedMemorySize, DYN_BYTES);
  void* args[] = { &p };
  (void)hipLaunchCooperativeKernel((void*)twistor_k, dim3(NBLK), dim3(NTHR), args,
                                   DYN_BYTES, stream);
}

// Round 4
// 16639.491 us; speedup vs baseline: 3.8798x; 1.0351x over previous
//
#include <hip/hip_runtime.h>

// TwistorLNN persistent cooperative kernel, round 4.
// - 8 waves/block (512 thr): one 16x16 MFMA tile per wave -> 2 waves/SIMD latency hiding.
// - Weights in LDS (150 KB dynamic), immune to coherence invalidations.
// - Barrier 1 (global norm sum): fence-free two-level value-carrying atomic reduction.
// - Barrier 2 (activation publish): rg-local (32 blocks), publishes are write-through
//   agent-scope atomic u32 stores; consumers run one acquire-only fence (buffer_inv).
// - res LDS stride 18 -> conflict-free (2-way) MFMA result staging.
// - MFMA 16x16x32 bf16 with bf16x3 compensation (AhBh + AhBl + AlBh).

namespace {

constexpr int Tn = 512, Bn = 256, INn = 256, Hn = 512, On = 64;
constexpr int NBLK = 256, NT = 512, NTH = 256;  // main block=512thr, helper kernels 256
constexpr float DTc = 0.1f, TAU_MINc = 0.01f, TAU_MAXc = 1.0f, DZDT_MAXc = 10.0f, Z_MAXc = 100.0f;

constexpr int LDH = 520;   // padded K-stride (u16) for K=512 tiles
constexpr int LDI = 264;   // padded K-stride for K=256 tiles

// dynamic-LDS layout, u16 offsets (byte offsets 16B-aligned)
constexpr int O_WRH = 0,     O_WRL = 8320,  O_WIH = 16640, O_WIL = 24960;
constexpr int O_WTH = 33280, O_WTL = 41600;
constexpr int O_UH  = 49920, O_UL  = 54144;
constexpr int O_OH  = 58368, O_OL  = 66688;
constexpr int DYN_BYTES = 75008 * 2;  // 150016

typedef short short8 __attribute__((ext_vector_type(8)));
typedef float f32x4 __attribute__((ext_vector_type(4)));
typedef unsigned short u16;
typedef unsigned int u32;

#define MFMA(a, b, c) __builtin_amdgcn_mfma_f32_16x16x32_bf16((a), (b), (c), 0, 0, 0)
#define AT_RLX __ATOMIC_RELAXED
#define SC_AGT __HIP_MEMORY_SCOPE_AGENT

struct P {
  const float *x, *wtb, *taubias, *outb;
  u16 *tre_h, *tre_l, *tim_h, *tim_l, *zmod_h, *zmod_l, *zreh, *zrel;
  u16 *xh, *xl;
  u16 *wr_h, *wr_l, *wi_h, *wi_l, *wt_h, *wt_l, *uh, *ul, *oh, *ol;
  float *bias_re, *bias_im;
  float *accL, *accT;
  int *cntL, *cntT, *cnt2;
  float *out;
};

__device__ __forceinline__ u16 f2bf(float f) {
  union { float f; unsigned u; } v; v.f = f;
  unsigned r = v.u + 0x7fffu + ((v.u >> 16) & 1u);
  return (u16)(r >> 16);
}
__device__ __forceinline__ float bf2f(u16 h) {
  union { unsigned u; float f; } v; v.u = ((unsigned)h) << 16;
  return v.f;
}
__device__ __forceinline__ void split_store(float v, u16* hi, u16* lo) {
  u16 h = f2bf(v); *hi = h; *lo = f2bf(v - bf2f(h));
}
__device__ __forceinline__ void split2(float v, u16& h, u16& l) {
  h = f2bf(v); l = f2bf(v - bf2f(h));
}
__device__ __forceinline__ u32 pk(u16 a, u16 b) { return (u32)a | ((u32)b << 16); }

__device__ __forceinline__ float fsig(float x) { return 1.f / (1.f + __expf(-x)); }
__device__ __forceinline__ float ftanh(float x) {
  float e = __expf(-2.f * fabsf(x));
  float t = (1.f - e) / (1.f + e);
  return copysignf(t, x);
}

// ---------------- prep: gate + hi/lo split weights, fold biases ----------------
__global__ void prep_k(const float* Wr, const float* mr, const float* Wi, const float* mi,
                       const float* Wt, const float* U, const float* Ow,
                       const float* Wrb, const float* Ub, const float* brl,
                       const float* Wib, const float* bim, P p) {
  int i = blockIdx.x * NTH + threadIdx.x;
  if (i < Hn * Hn) {
    float g = fsig(mr[i]);
    split_store(Wr[i] * g, &p.wr_h[i], &p.wr_l[i]);
    g = fsig(mi[i]);
    split_store(Wi[i] * g, &p.wi_h[i], &p.wi_l[i]);
    split_store(Wt[i], &p.wt_h[i], &p.wt_l[i]);
  }
  if (i < Hn * INn) split_store(U[i], &p.uh[i], &p.ul[i]);
  if (i < On * Hn)  split_store(Ow[i], &p.oh[i], &p.ol[i]);
  if (i < Hn) {
    p.bias_re[i] = Wrb[i] + Ub[i] + brl[i];
    p.bias_im[i] = Wib[i] + Ub[i] + bim[i];
  }
}

// ---------------- init: Z_0 activations, x[0] split, zero barrier slots ----------------
__global__ void init_k(P p) {
  int i = blockIdx.x * NTH + threadIdx.x;
  if (i < Bn * Hn) {
    p.tre_h[i] = 0; p.tre_l[i] = 0; p.tim_h[i] = 0; p.tim_l[i] = 0;
    p.zreh[i] = 0; p.zrel[i] = 0;
    split_store(1e-6f, &p.zmod_h[i], &p.zmod_l[i]);
  }
  if (i < Bn * INn) split_store(p.x[i], &p.xh[i], &p.xl[i]);
  if (i < Tn * 32) { p.accL[i] = 0.f; p.cntL[i] = 0; }
  if (i < Tn)      { p.accT[i] = 0.f; p.cntT[i] = 0; }
  if (i < Tn * 8)  p.cnt2[i] = 0;
}

// ---------------- stage one 16-row weight tile into LDS ----------------
template <int K, int LD>
__device__ __forceinline__ void stage(const u16* __restrict__ src, u16* dst, int grow0, int tid) {
  constexpr int CH = K / 8;
#pragma unroll
  for (int i = tid; i < 16 * CH; i += NT) {
    int n = i / CH, kk = (i % CH) * 8;
    *(short8*)(dst + n * LD + kk) = *(const short8*)(src + (size_t)(grow0 + n) * K + kk);
  }
}

// ---------------- one 16x16 tile: A global (h+l), B LDS (h+l), bf16x3 ----------------
template <int K, int LDB>
__device__ __forceinline__ f32x4 mm1(const u16* __restrict__ ah, const u16* __restrict__ al,
                                     const u16* bh, const u16* bl,
                                     int arow0, int lda, int m, int q) {
  f32x4 acc = {0.f, 0.f, 0.f, 0.f};
  const u16* aph = ah + (size_t)(arow0 + m) * lda + q * 8;
  const u16* apl = al + (size_t)(arow0 + m) * lda + q * 8;
  const u16* bph = bh + m * LDB + q * 8;
  const u16* bpl = bl + m * LDB + q * 8;
#pragma unroll 8
  for (int k0 = 0; k0 < K; k0 += 32) {
    short8 Bh = *(const short8*)(bph + k0);
    short8 Bl = *(const short8*)(bpl + k0);
    short8 Ah = *(const short8*)(aph + k0);
    short8 Al = *(const short8*)(apl + k0);
    acc = MFMA(Ah, Bh, acc); acc = MFMA(Ah, Bl, acc); acc = MFMA(Al, Bh, acc);
  }
  return acc;
}

// ---------------- one y-tile: zre (global) x out_w (LDS) ----------------
__device__ __forceinline__ void yjob(const P& p, const u16* bh, const u16* bl,
                                     int rowbase, int ocol0, int ty, int m, int q) {
  f32x4 acc = mm1<Hn, LDH>(p.zreh, p.zrel, bh, bl, rowbase, Hn, m, q);
  int o = ocol0 + m;
  float ob = p.outb[o];
#pragma unroll
  for (int i = 0; i < 4; ++i)
    p.out[((size_t)ty * Bn + rowbase + q * 4 + i) * On + o] = acc[i] + ob;
}

// ---------------- persistent loop kernel ----------------
__global__ void __launch_bounds__(NT, 1) twistor_k(P p) {
  extern __shared__ __align__(16) u16 smem[];
  __shared__ float res[4][32][18];   // stride-18: wave quads land on disjoint bank quarters
  __shared__ float sb[4][16];        // bias_re, bias_im, wtb, taubias tiles
  __shared__ float wsum[8];
  __shared__ float sscale;

  const int bid = blockIdx.x, tid = threadIdx.x;
  const int rg = bid & 7, cg = bid >> 3;
  const int wave = tid >> 6, lane = tid & 63, m = lane & 15, q = lane >> 4;
  const int row0 = rg * 32, col0 = cg * 16;
  const bool yblk = (cg >= 8 && cg < 16);
  const int yk = cg - 8;
  const int yrowbase = row0 + 16 * (yk & 1);
  const int yocol = (yk >> 1) * 16;

  // one-time: stage this block's weight tiles into LDS
  stage<Hn, LDH>(p.wr_h, smem + O_WRH, col0, tid);
  stage<Hn, LDH>(p.wr_l, smem + O_WRL, col0, tid);
  stage<Hn, LDH>(p.wi_h, smem + O_WIH, col0, tid);
  stage<Hn, LDH>(p.wi_l, smem + O_WIL, col0, tid);
  stage<Hn, LDH>(p.wt_h, smem + O_WTH, col0, tid);
  stage<Hn, LDH>(p.wt_l, smem + O_WTL, col0, tid);
  stage<INn, LDI>(p.uh, smem + O_UH, col0, tid);
  stage<INn, LDI>(p.ul, smem + O_UL, col0, tid);
  int orow0 = yblk ? yocol : 0;
  stage<Hn, LDH>(p.oh, smem + O_OH, orow0, tid);
  stage<Hn, LDH>(p.ol, smem + O_OL, orow0, tid);
  if (tid < 16) {
    sb[0][tid] = p.bias_re[col0 + tid];
    sb[1][tid] = p.bias_im[col0 + tid];
    sb[2][tid] = p.wtb[col0 + tid];
    sb[3][tid] = p.taubias[col0 + tid];
  }
  __syncthreads();

  // thread owns element (row0 + r, col0 + c); state in registers
  const int r = tid >> 4, c = tid & 15;
  const size_t idx = (size_t)(row0 + r) * Hn + col0 + c;
  const bool evenl = ((lane & 1) == 0);
  float zr = 0.f, zi = 0.f;

  for (int t = 0; t < Tn; ++t) {
    // ===== phase A: 8 MFMA tile jobs (one per wave) from published Z_t =====
    {
      const int job = wave >> 1, half = wave & 1;
      if (wave < 6) {
        const u16 *ah_, *al_, *bh_, *bl_;
        if (job == 0)      { ah_ = p.tre_h;  al_ = p.tre_l;  bh_ = smem + O_WRH; bl_ = smem + O_WRL; }
        else if (job == 1) { ah_ = p.tim_h;  al_ = p.tim_l;  bh_ = smem + O_WIH; bl_ = smem + O_WIL; }
        else               { ah_ = p.zmod_h; al_ = p.zmod_l; bh_ = smem + O_WTH; bl_ = smem + O_WTL; }
        f32x4 a = mm1<Hn, LDH>(ah_, al_, bh_, bl_, row0 + 16 * half, Hn, m, q);
#pragma unroll
        for (int i = 0; i < 4; ++i) res[job][16 * half + q * 4 + i][m] = a[i];
      } else if (wave == 6) {
        f32x4 a = mm1<INn, LDI>(p.xh, p.xl, smem + O_UH, smem + O_UL, row0, INn, m, q);
#pragma unroll
        for (int i = 0; i < 4; ++i) res[3][q * 4 + i][m] = a[i];
        if (yblk) {
          f32x4 b = mm1<INn, LDI>(p.xh, p.xl, smem + O_UH, smem + O_UL, row0 + 16, INn, m, q);
#pragma unroll
          for (int i = 0; i < 4; ++i) res[3][16 + q * 4 + i][m] = b[i];
        }
      } else {  // wave 7
        if (!yblk) {
          f32x4 a = mm1<INn, LDI>(p.xh, p.xl, smem + O_UH, smem + O_UL, row0 + 16, INn, m, q);
#pragma unroll
          for (int i = 0; i < 4; ++i) res[3][16 + q * 4 + i][m] = a[i];
        } else if (t > 0) {
          yjob(p, smem + O_OH, smem + O_OL, yrowbase, yocol, t - 1, m, q);
        }
      }
    }
    __syncthreads();

    // epilogue: dz, tau, d for own element (LDS/regs only)
    float dr, di;
    {
      float ux = res[3][r][c];
      float dzre = -zr + res[0][r][c] + ux + sb[0][c];
      float dzim = -zi + res[1][r][c] + ux + sb[1][c];
      float tau = fsig(res[2][r][c] + sb[2][c]);
      tau = fminf(fmaxf(tau + sb[3][c], TAU_MINc), TAU_MAXc) + 1e-6f;
      float rt = 1.f / tau;
      dr = fminf(fmaxf(dzre * rt, -DZDT_MAXc), DZDT_MAXc);
      di = fminf(fmaxf(dzim * rt, -DZDT_MAXc), DZDT_MAXc);
    }
    float pn = sqrtf(dr * dr + di * di + 1e-12f);
#pragma unroll
    for (int off = 32; off > 0; off >>= 1) pn += __shfl_down(pn, off, 64);
    if (lane == 0) wsum[wave] = pn;
    __syncthreads();

    // ===== barrier 1: fence-free two-level value-carrying reduction =====
    if (tid == 0) {
      float s = 0.f;
#pragma unroll
      for (int w = 0; w < 8; ++w) s += wsum[w];
      int g = bid >> 3;
      __hip_atomic_fetch_add(&p.accL[t * 32 + g], s, AT_RLX, SC_AGT);
      __builtin_amdgcn_s_waitcnt(0);
      int a = __hip_atomic_fetch_add(&p.cntL[t * 32 + g], 1, AT_RLX, SC_AGT);
      if (a == 7) {
        float gs = __hip_atomic_load(&p.accL[t * 32 + g], AT_RLX, SC_AGT);
        __hip_atomic_fetch_add(&p.accT[t], gs, AT_RLX, SC_AGT);
        __builtin_amdgcn_s_waitcnt(0);
        __hip_atomic_fetch_add(&p.cntT[t], 1, AT_RLX, SC_AGT);
      }
      while (__hip_atomic_load(&p.cntT[t], AT_RLX, SC_AGT) != 32)
        __builtin_amdgcn_s_sleep(1);
      float total = __hip_atomic_load(&p.accT[t], AT_RLX, SC_AGT);
      float mean = total * (1.f / (float)(Bn * Hn));
      sscale = (mean > 0.5f * DZDT_MAXc) ? (0.5f * DZDT_MAXc) / (mean + 1e-6f) : 1.f;
    }
    __syncthreads();
    float scale = sscale;

    // ===== phase B: z update in regs, publish Z_{t+1} via write-through atomics =====
    zr = fminf(fmaxf(zr + DTc * scale * dr, -Z_MAXc), Z_MAXc);
    zi = fminf(fmaxf(zi + DTc * scale * di, -Z_MAXc), Z_MAXc);
    {
      float vs[4];
      vs[0] = ftanh(zr); vs[1] = ftanh(zi);
      vs[2] = sqrtf(zr * zr + zi * zi + 1e-12f); vs[3] = zr;
      u16* dsth[4] = { p.tre_h, p.tim_h, p.zmod_h, p.zreh };
      u16* dstl[4] = { p.tre_l, p.tim_l, p.zmod_l, p.zrel };
#pragma unroll
      for (int k = 0; k < 4; ++k) {
        u16 h, l; split2(vs[k], h, l);
        int nh = __shfl_down((int)h, 1, 64);
        int nl = __shfl_down((int)l, 1, 64);
        if (evenl) {
          __hip_atomic_store((u32*)(dsth[k] + idx), pk(h, (u16)nh), AT_RLX, SC_AGT);
          __hip_atomic_store((u32*)(dstl[k] + idx), pk(l, (u16)nl), AT_RLX, SC_AGT);
        }
      }
    }
    if (tid < 256 && t + 1 < Tn) {   // x split for t+1; row rg*32+cg (rg-local consumers)
      int bro = rg * 32 + cg;
      float v = p.x[(size_t)(t + 1) * (Bn * INn) + (size_t)bro * INn + tid];
      u16 h, l; split2(v, h, l);
      int nh = __shfl_down((int)h, 1, 64);
      int nl = __shfl_down((int)l, 1, 64);
      if (!(tid & 1)) {
        size_t xi = (size_t)bro * INn + tid;
        __hip_atomic_store((u32*)(p.xh + xi), pk(h, (u16)nh), AT_RLX, SC_AGT);
        __hip_atomic_store((u32*)(p.xl + xi), pk(l, (u16)nl), AT_RLX, SC_AGT);
      }
    }

    // ===== barrier 2: rg-local arrival (publishes drained by __syncthreads) =====
    __syncthreads();   // s_barrier semantics drain all waves' outstanding stores
    if (tid == 0) {
      __hip_atomic_fetch_add(&p.cnt2[t * 8 + rg], 1, AT_RLX, SC_AGT);
      while (__hip_atomic_load(&p.cnt2[t * 8 + rg], AT_RLX, SC_AGT) != 32)
        __builtin_amdgcn_s_sleep(1);
    }
    __syncthreads();
    __builtin_amdgcn_fence(__ATOMIC_ACQUIRE, "agent");  // inv stale L1/L2 lines, no wb
  }

  // final y_{T-1} from Z_T
  if (yblk && wave == 7) yjob(p, smem + O_OH, smem + O_OL, yrowbase, yocol, Tn - 1, m, q);
}

}  // namespace

extern "C" void kernel_launch(void* const* d_in, const int* in_sizes, int n_in,
                              void* d_out, int out_size, void* d_ws, size_t ws_size,
                              hipStream_t stream) {
  (void)in_sizes; (void)n_in; (void)out_size; (void)ws_size;
  char* w = (char*)d_ws;
  auto alloc = [&](size_t bytes) -> char* {
    char* r = w; w += (bytes + 255) & ~(size_t)255; return r;
  };

  P p;
  p.x       = (const float*)d_in[0];
  const float* Wr  = (const float*)d_in[1];
  const float* Wrb = (const float*)d_in[2];
  const float* Wi  = (const float*)d_in[3];
  const float* Wib = (const float*)d_in[4];
  const float* U   = (const float*)d_in[5];
  const float* Ub  = (const float*)d_in[6];
  const float* Wt  = (const float*)d_in[7];
  p.wtb     = (const float*)d_in[8];
  const float* mr  = (const float*)d_in[9];
  const float* mi  = (const float*)d_in[10];
  p.taubias = (const float*)d_in[11];
  const float* brl = (const float*)d_in[12];
  const float* bim = (const float*)d_in[13];
  const float* Ow  = (const float*)d_in[14];
  p.outb    = (const float*)d_in[15];

  p.tre_h = (u16*)alloc(Bn * Hn * 2);  p.tre_l = (u16*)alloc(Bn * Hn * 2);
  p.tim_h = (u16*)alloc(Bn * Hn * 2);  p.tim_l = (u16*)alloc(Bn * Hn * 2);
  p.zmod_h = (u16*)alloc(Bn * Hn * 2); p.zmod_l = (u16*)alloc(Bn * Hn * 2);
  p.zreh = (u16*)alloc(Bn * Hn * 2);   p.zrel = (u16*)alloc(Bn * Hn * 2);
  p.xh = (u16*)alloc(Bn * INn * 2);    p.xl = (u16*)alloc(Bn * INn * 2);
  p.wr_h = (u16*)alloc(Hn * Hn * 2);   p.wr_l = (u16*)alloc(Hn * Hn * 2);
  p.wi_h = (u16*)alloc(Hn * Hn * 2);   p.wi_l = (u16*)alloc(Hn * Hn * 2);
  p.wt_h = (u16*)alloc(Hn * Hn * 2);   p.wt_l = (u16*)alloc(Hn * Hn * 2);
  p.uh = (u16*)alloc(Hn * INn * 2);    p.ul = (u16*)alloc(Hn * INn * 2);
  p.oh = (u16*)alloc(On * Hn * 2);     p.ol = (u16*)alloc(On * Hn * 2);
  p.bias_re = (float*)alloc(Hn * 4);   p.bias_im = (float*)alloc(Hn * 4);
  p.accL = (float*)alloc(Tn * 32 * 4);
  p.cntL = (int*)alloc(Tn * 32 * 4);
  p.accT = (float*)alloc(Tn * 4);
  p.cntT = (int*)alloc(Tn * 4);
  p.cnt2 = (int*)alloc(Tn * 8 * 4);
  p.out = (float*)d_out;

  prep_k<<<(Hn * Hn + NTH - 1) / NTH, NTH, 0, stream>>>(Wr, mr, Wi, mi, Wt, U, Ow,
                                                        Wrb, Ub, brl, Wib, bim, p);
  init_k<<<(Bn * Hn + NTH - 1) / NTH, NTH, 0, stream>>>(p);

  (void)hipFuncSetAttribute((const void*)twistor_k,
                            hipFuncAttributeMaxDynamicSharedMemorySize, DYN_BYTES);
  void* args[] = { &p };
  (void)hipLaunchCooperativeKernel((void*)twistor_k, dim3(NBLK), dim3(NT), args,
                                   DYN_BYTES, stream);
}

// Round 5
// 8573.473 us; speedup vs baseline: 7.5300x; 1.9408x over previous
//
#include <hip/hip_runtime.h>

// TwistorLNN persistent cooperative kernel, round 5.
// Key change vs R4: keep published activations resident in the consumers' XCD L2.
//  - rg-group (32 blocks sharing batch rows) is XCD-colocated under the bid%8
//    round-robin mapping; verified at runtime via s_getreg(HW_REG_XCC_ID).
//  - Fast path: plain stores (write-through L1 -> shared L2), per-step L1-only
//    buffer_inv at consumers, value-carrying relaxed agent atomics for the norm
//    scalar and barrier counters. NO agent fences -> L2 never invalidated.
//  - Slow path (mapping check fails): producer threadfence + consumer agent
//    acquire fence per step (R3 behavior, correct on any mapping).
//  - zmod lo-part dropped (tau tolerant); x-split double-buffered & prefetched.

namespace {

constexpr int Tn = 512, Bn = 256, INn = 256, Hn = 512, On = 64;
constexpr int NBLK = 256, NT = 512, NTH = 256;
constexpr float DTc = 0.1f, TAU_MINc = 0.01f, TAU_MAXc = 1.0f, DZDT_MAXc = 10.0f, Z_MAXc = 100.0f;

constexpr int LDH = 520;   // padded K-stride (u16), 16B-aligned rows
constexpr int LDI = 264;

constexpr int O_WRH = 0,     O_WRL = 8320,  O_WIH = 16640, O_WIL = 24960;
constexpr int O_WTH = 33280, O_WTL = 41600;
constexpr int O_UH  = 49920, O_UL  = 54144;
constexpr int O_OH  = 58368, O_OL  = 66688;
constexpr int DYN_BYTES = 75008 * 2;  // 150016

typedef short short8 __attribute__((ext_vector_type(8)));
typedef float f32x4 __attribute__((ext_vector_type(4)));
typedef unsigned short u16;
typedef unsigned int u32;

#define MFMA(a, b, c) __builtin_amdgcn_mfma_f32_16x16x32_bf16((a), (b), (c), 0, 0, 0)
#define AT_RLX __ATOMIC_RELAXED
#define SC_AGT __HIP_MEMORY_SCOPE_AGENT

struct P {
  const float *x, *wtb, *taubias, *outb;
  u16 *tre_h, *tre_l, *tim_h, *tim_l, *zmod_h, *zreh, *zrel;
  u16 *xh, *xl;             // double-buffered: [2][Bn*INn]
  u16 *wr_h, *wr_l, *wi_h, *wi_l, *wt_h, *wt_l, *uh, *ul, *oh, *ol;
  float *bias_re, *bias_im;
  float *accL, *accT;
  int *cntL, *cntT, *cnt2, *barF, *xcc;
  float *out;
};

__device__ __forceinline__ u16 f2bf(float f) {
  union { float f; unsigned u; } v; v.f = f;
  unsigned r = v.u + 0x7fffu + ((v.u >> 16) & 1u);
  return (u16)(r >> 16);
}
__device__ __forceinline__ float bf2f(u16 h) {
  union { unsigned u; float f; } v; v.u = ((unsigned)h) << 16;
  return v.f;
}
__device__ __forceinline__ void split_store(float v, u16* hi, u16* lo) {
  u16 h = f2bf(v); *hi = h; *lo = f2bf(v - bf2f(h));
}
__device__ __forceinline__ void split2(float v, u16& h, u16& l) {
  h = f2bf(v); l = f2bf(v - bf2f(h));
}
__device__ __forceinline__ u32 pk(u16 a, u16 b) { return (u32)a | ((u32)b << 16); }

__device__ __forceinline__ float fsig(float x) { return 1.f / (1.f + __expf(-x)); }
__device__ __forceinline__ float ftanh(float x) {
  float e = __expf(-2.f * fabsf(x));
  float t = (1.f - e) / (1.f + e);
  return copysignf(t, x);
}
__device__ __forceinline__ void l1_inv() {   // invalidate this CU's vector L1 only
  asm volatile("buffer_inv\n\ts_waitcnt vmcnt(0)" ::: "memory");
}

// ---------------- prep ----------------
__global__ void prep_k(const float* Wr, const float* mr, const float* Wi, const float* mi,
                       const float* Wt, const float* U, const float* Ow,
                       const float* Wrb, const float* Ub, const float* brl,
                       const float* Wib, const float* bim, P p) {
  int i = blockIdx.x * NTH + threadIdx.x;
  if (i < Hn * Hn) {
    float g = fsig(mr[i]);
    split_store(Wr[i] * g, &p.wr_h[i], &p.wr_l[i]);
    g = fsig(mi[i]);
    split_store(Wi[i] * g, &p.wi_h[i], &p.wi_l[i]);
    split_store(Wt[i], &p.wt_h[i], &p.wt_l[i]);
  }
  if (i < Hn * INn) split_store(U[i], &p.uh[i], &p.ul[i]);
  if (i < On * Hn)  split_store(Ow[i], &p.oh[i], &p.ol[i]);
  if (i < Hn) {
    p.bias_re[i] = Wrb[i] + Ub[i] + brl[i];
    p.bias_im[i] = Wib[i] + Ub[i] + bim[i];
  }
}

// ---------------- init ----------------
__global__ void init_k(P p) {
  int i = blockIdx.x * NTH + threadIdx.x;
  if (i < Bn * Hn) {
    p.tre_h[i] = 0; p.tre_l[i] = 0; p.tim_h[i] = 0; p.tim_l[i] = 0;
    p.zreh[i] = 0; p.zrel[i] = 0;
    p.zmod_h[i] = f2bf(1e-6f);
  }
  if (i < Bn * INn) split_store(p.x[i], &p.xh[i], &p.xl[i]);  // buffer 0
  if (i < Tn * 32) { p.accL[i] = 0.f; p.cntL[i] = 0; }
  if (i < Tn)      { p.accT[i] = 0.f; p.cntT[i] = 0; }
  if (i < Tn * 8)  p.cnt2[i] = 0;
  if (i < 64)      p.barF[i] = 0;
}

// ---------------- one-time full-fence grid barrier ----------------
__device__ void gbarF(int* bar) {
  __syncthreads();
  if (threadIdx.x == 0) {
    __threadfence();
    int g = __hip_atomic_load(bar + 32, AT_RLX, SC_AGT);
    int a = __hip_atomic_fetch_add(bar, 1, __ATOMIC_ACQ_REL, SC_AGT);
    if (a == NBLK - 1) {
      __hip_atomic_store(bar, 0, AT_RLX, SC_AGT);
      __hip_atomic_store(bar + 32, g + 1, __ATOMIC_RELEASE, SC_AGT);
    } else {
      while (__hip_atomic_load(bar + 32, __ATOMIC_ACQUIRE, SC_AGT) == g)
        __builtin_amdgcn_s_sleep(2);
    }
    __threadfence();
  }
  __syncthreads();
}

// ---------------- weight tile staging into LDS ----------------
template <int K, int LD>
__device__ __forceinline__ void stage(const u16* __restrict__ src, u16* dst, int grow0, int tid) {
  constexpr int CH = K / 8;
#pragma unroll
  for (int i = tid; i < 16 * CH; i += NT) {
    int n = i / CH, kk = (i % CH) * 8;
    *(short8*)(dst + n * LD + kk) = *(const short8*)(src + (size_t)(grow0 + n) * K + kk);
  }
}

// ---------------- 16x16 tile, A(h+l) global x B(h+l) LDS, bf16x3 ----------------
template <int K, int LDB>
__device__ __forceinline__ f32x4 mm1(const u16* __restrict__ ah, const u16* __restrict__ al,
                                     const u16* bh, const u16* bl,
                                     int arow0, int lda, int m, int q) {
  f32x4 acc = {0.f, 0.f, 0.f, 0.f};
  const u16* aph = ah + (size_t)(arow0 + m) * lda + q * 8;
  const u16* apl = al + (size_t)(arow0 + m) * lda + q * 8;
  const u16* bph = bh + m * LDB + q * 8;
  const u16* bpl = bl + m * LDB + q * 8;
#pragma unroll 8
  for (int k0 = 0; k0 < K; k0 += 32) {
    short8 Bh = *(const short8*)(bph + k0);
    short8 Bl = *(const short8*)(bpl + k0);
    short8 Ah = *(const short8*)(aph + k0);
    short8 Al = *(const short8*)(apl + k0);
    acc = MFMA(Ah, Bh, acc); acc = MFMA(Ah, Bl, acc); acc = MFMA(Al, Bh, acc);
  }
  return acc;
}

// A hi-only variant (for |z| @ Wt: tau path tolerates bf16 A)
template <int K, int LDB>
__device__ __forceinline__ f32x4 mm1h(const u16* __restrict__ ah,
                                      const u16* bh, const u16* bl,
                                      int arow0, int lda, int m, int q) {
  f32x4 acc = {0.f, 0.f, 0.f, 0.f};
  const u16* aph = ah + (size_t)(arow0 + m) * lda + q * 8;
  const u16* bph = bh + m * LDB + q * 8;
  const u16* bpl = bl + m * LDB + q * 8;
#pragma unroll 8
  for (int k0 = 0; k0 < K; k0 += 32) {
    short8 Bh = *(const short8*)(bph + k0);
    short8 Bl = *(const short8*)(bpl + k0);
    short8 Ah = *(const short8*)(aph + k0);
    acc = MFMA(Ah, Bh, acc); acc = MFMA(Ah, Bl, acc);
  }
  return acc;
}

__device__ __forceinline__ void yjob(const P& p, const u16* bh, const u16* bl,
                                     int rowbase, int ocol0, int ty, int m, int q) {
  f32x4 acc = mm1<Hn, LDH>(p.zreh, p.zrel, bh, bl, rowbase, Hn, m, q);
  int o = ocol0 + m;
  float ob = p.outb[o];
#pragma unroll
  for (int i = 0; i < 4; ++i)
    p.out[((size_t)ty * Bn + rowbase + q * 4 + i) * On + o] = acc[i] + ob;
}

// ---------------- persistent loop kernel ----------------
__global__ void __launch_bounds__(NT, 1) twistor_k(P p) {
  extern __shared__ __align__(16) u16 smem[];
  __shared__ float res[4][32][18];
  __shared__ float sb[4][16];
  __shared__ float wsum[8];
  __shared__ float sscale;
  __shared__ int sfast;

  const int bid = blockIdx.x, tid = threadIdx.x;
  const int rg = bid & 7, cg = bid >> 3;       // rg-group co-located per XCD (verified)
  const int wave = tid >> 6, lane = tid & 63, m = lane & 15, q = lane >> 4;
  const int row0 = rg * 32, col0 = cg * 16;
  const bool yblk = (cg >= 8 && cg < 16);
  const int yk = cg - 8;
  const int yrowbase = row0 + 16 * (yk & 1);
  const int yocol = (yk >> 1) * 16;

  stage<Hn, LDH>(p.wr_h, smem + O_WRH, col0, tid);
  stage<Hn, LDH>(p.wr_l, smem + O_WRL, col0, tid);
  stage<Hn, LDH>(p.wi_h, smem + O_WIH, col0, tid);
  stage<Hn, LDH>(p.wi_l, smem + O_WIL, col0, tid);
  stage<Hn, LDH>(p.wt_h, smem + O_WTH, col0, tid);
  stage<Hn, LDH>(p.wt_l, smem + O_WTL, col0, tid);
  stage<INn, LDI>(p.uh, smem + O_UH, col0, tid);
  stage<INn, LDI>(p.ul, smem + O_UL, col0, tid);
  int orow0 = yblk ? yocol : 0;
  stage<Hn, LDH>(p.oh, smem + O_OH, orow0, tid);
  stage<Hn, LDH>(p.ol, smem + O_OL, orow0, tid);
  if (tid < 16) {
    sb[0][tid] = p.bias_re[col0 + tid];
    sb[1][tid] = p.bias_im[col0 + tid];
    sb[2][tid] = p.wtb[col0 + tid];
    sb[3][tid] = p.taubias[col0 + tid];
  }

  // ---- runtime XCD-mapping check: is each rg-group on one XCD? ----
  int xccid;
  asm volatile("s_getreg_b32 %0, hwreg(HW_REG_XCC_ID)" : "=s"(xccid));
  if (tid == 0) {
    __hip_atomic_store(&p.xcc[bid], xccid, AT_RLX, SC_AGT);
    sfast = 1;
  }
  gbarF(p.barF);   // full fences; also covers weight staging ordering (LDS is local anyway)
  if (tid < NBLK) {
    int v = __hip_atomic_load(&p.xcc[tid], AT_RLX, SC_AGT);
    int r = __hip_atomic_load(&p.xcc[tid & 7], AT_RLX, SC_AGT);
    if (v != r) atomicAnd(&sfast, 0);
  }
  __syncthreads();
  const bool fast = (sfast != 0);

  const int r = tid >> 4, c = tid & 15;
  const size_t idx = (size_t)(row0 + r) * Hn + col0 + c;
  const bool evenl = ((lane & 1) == 0);
  float zr = 0.f, zi = 0.f;

  for (int t = 0; t < Tn; ++t) {
    const u16* xh_r = p.xh + (size_t)(t & 1) * (Bn * INn);
    const u16* xl_r = p.xl + (size_t)(t & 1) * (Bn * INn);

    // prefetch next x row (double-buffered target, no WAR hazard)
    float xv = 0.f;
    if (tid < 256 && t + 1 < Tn)
      xv = p.x[(size_t)(t + 1) * (Bn * INn) + (size_t)(rg * 32 + cg) * INn + tid];

    // ===== phase A: MFMA jobs from published Z_t =====
    {
      const int job = wave >> 1, half = wave & 1;
      if (wave < 4) {
        const u16 *ah_ = (job == 0) ? p.tre_h : p.tim_h;
        const u16 *al_ = (job == 0) ? p.tre_l : p.tim_l;
        const u16 *bh_ = smem + ((job == 0) ? O_WRH : O_WIH);
        const u16 *bl_ = smem + ((job == 0) ? O_WRL : O_WIL);
        f32x4 a = mm1<Hn, LDH>(ah_, al_, bh_, bl_, row0 + 16 * half, Hn, m, q);
#pragma unroll
        for (int i = 0; i < 4; ++i) res[job][16 * half + q * 4 + i][m] = a[i];
      } else if (wave < 6) {
        f32x4 a = mm1h<Hn, LDH>(p.zmod_h, smem + O_WTH, smem + O_WTL,
                                row0 + 16 * half, Hn, m, q);
#pragma unroll
        for (int i = 0; i < 4; ++i) res[2][16 * half + q * 4 + i][m] = a[i];
      } else if (wave == 6) {
        f32x4 a = mm1<INn, LDI>(xh_r, xl_r, smem + O_UH, smem + O_UL, row0, INn, m, q);
#pragma unroll
        for (int i = 0; i < 4; ++i) res[3][q * 4 + i][m] = a[i];
        if (yblk) {
          f32x4 b = mm1<INn, LDI>(xh_r, xl_r, smem + O_UH, smem + O_UL, row0 + 16, INn, m, q);
#pragma unroll
          for (int i = 0; i < 4; ++i) res[3][16 + q * 4 + i][m] = b[i];
        }
      } else {
        if (!yblk) {
          f32x4 a = mm1<INn, LDI>(xh_r, xl_r, smem + O_UH, smem + O_UL, row0 + 16, INn, m, q);
#pragma unroll
          for (int i = 0; i < 4; ++i) res[3][16 + q * 4 + i][m] = a[i];
        } else if (t > 0) {
          yjob(p, smem + O_OH, smem + O_OL, yrowbase, yocol, t - 1, m, q);
        }
      }
    }
    __syncthreads();

    // epilogue: dz, tau, d for own element
    float dr, di;
    {
      float ux = res[3][r][c];
      float dzre = -zr + res[0][r][c] + ux + sb[0][c];
      float dzim = -zi + res[1][r][c] + ux + sb[1][c];
      float tau = fsig(res[2][r][c] + sb[2][c]);
      tau = fminf(fmaxf(tau + sb[3][c], TAU_MINc), TAU_MAXc) + 1e-6f;
      float rt = 1.f / tau;
      dr = fminf(fmaxf(dzre * rt, -DZDT_MAXc), DZDT_MAXc);
      di = fminf(fmaxf(dzim * rt, -DZDT_MAXc), DZDT_MAXc);
    }
    float pn = sqrtf(dr * dr + di * di + 1e-12f);
#pragma unroll
    for (int off = 32; off > 0; off >>= 1) pn += __shfl_down(pn, off, 64);
    if (lane == 0) wsum[wave] = pn;
    __syncthreads();

    // ===== barrier 1: fence-free value-carrying global reduction =====
    if (tid == 0) {
      float s = 0.f;
#pragma unroll
      for (int w = 0; w < 8; ++w) s += wsum[w];
      int g = bid >> 3;
      __hip_atomic_fetch_add(&p.accL[t * 32 + g], s, AT_RLX, SC_AGT);
      __builtin_amdgcn_s_waitcnt(0);
      int a = __hip_atomic_fetch_add(&p.cntL[t * 32 + g], 1, AT_RLX, SC_AGT);
      if (a == 7) {
        float gs = __hip_atomic_load(&p.accL[t * 32 + g], AT_RLX, SC_AGT);
        __hip_atomic_fetch_add(&p.accT[t], gs, AT_RLX, SC_AGT);
        __builtin_amdgcn_s_waitcnt(0);
        __hip_atomic_fetch_add(&p.cntT[t], 1, AT_RLX, SC_AGT);
      }
      while (__hip_atomic_load(&p.cntT[t], AT_RLX, SC_AGT) != 32)
        __builtin_amdgcn_s_sleep(1);
      float total = __hip_atomic_load(&p.accT[t], AT_RLX, SC_AGT);
      float mean = total * (1.f / (float)(Bn * Hn));
      sscale = (mean > 0.5f * DZDT_MAXc) ? (0.5f * DZDT_MAXc) / (mean + 1e-6f) : 1.f;
    }
    __syncthreads();
    float scale = sscale;

    // ===== phase B: z update, publish Z_{t+1} with PLAIN stores =====
    zr = fminf(fmaxf(zr + DTc * scale * dr, -Z_MAXc), Z_MAXc);
    zi = fminf(fmaxf(zi + DTc * scale * di, -Z_MAXc), Z_MAXc);
    {
      u16 h, l; int nh, nl;
      split2(ftanh(zr), h, l);
      nh = __shfl_down((int)h, 1, 64); nl = __shfl_down((int)l, 1, 64);
      if (evenl) { *(u32*)(p.tre_h + idx) = pk(h, (u16)nh); *(u32*)(p.tre_l + idx) = pk(l, (u16)nl); }
      split2(ftanh(zi), h, l);
      nh = __shfl_down((int)h, 1, 64); nl = __shfl_down((int)l, 1, 64);
      if (evenl) { *(u32*)(p.tim_h + idx) = pk(h, (u16)nh); *(u32*)(p.tim_l + idx) = pk(l, (u16)nl); }
      h = f2bf(sqrtf(zr * zr + zi * zi + 1e-12f));
      nh = __shfl_down((int)h, 1, 64);
      if (evenl) *(u32*)(p.zmod_h + idx) = pk(h, (u16)nh);
      split2(zr, h, l);
      nh = __shfl_down((int)h, 1, 64); nl = __shfl_down((int)l, 1, 64);
      if (evenl) { *(u32*)(p.zreh + idx) = pk(h, (u16)nh); *(u32*)(p.zrel + idx) = pk(l, (u16)nl); }
    }
    if (tid < 256 && t + 1 < Tn) {
      u16 h, l; split2(xv, h, l);
      int nh = __shfl_down((int)h, 1, 64);
      int nl = __shfl_down((int)l, 1, 64);
      if (!(tid & 1)) {
        size_t xi = (size_t)((t + 1) & 1) * (Bn * INn) + (size_t)(rg * 32 + cg) * INn + tid;
        *(u32*)(p.xh + xi) = pk(h, (u16)nh);
        *(u32*)(p.xl + xi) = pk(l, (u16)nl);
      }
    }

    // ===== barrier 2: rg-local arrival =====
    __syncthreads();   // drains this block's stores to L2 (vmcnt(0) before s_barrier)
    if (tid == 0) {
      if (!fast) __threadfence();   // slow path: write back L2 for cross-XCD consumers
      __hip_atomic_fetch_add(&p.cnt2[t * 8 + rg], 1, AT_RLX, SC_AGT);
      while (__hip_atomic_load(&p.cnt2[t * 8 + rg], AT_RLX, SC_AGT) != 32)
        __builtin_amdgcn_s_sleep(1);
    }
    __syncthreads();
    if (fast) l1_inv();                                      // L1-only invalidate
    else __builtin_amdgcn_fence(__ATOMIC_ACQUIRE, "agent");  // full (slow path)
  }

  if (yblk && wave == 7) yjob(p, smem + O_OH, smem + O_OL, yrowbase, yocol, Tn - 1, m, q);
}

}  // namespace

extern "C" void kernel_launch(void* const* d_in, const int* in_sizes, int n_in,
                              void* d_out, int out_size, void* d_ws, size_t ws_size,
                              hipStream_t stream) {
  (void)in_sizes; (void)n_in; (void)out_size; (void)ws_size;
  char* w = (char*)d_ws;
  auto alloc = [&](size_t bytes) -> char* {
    char* r = w; w += (bytes + 255) & ~(size_t)255; return r;
  };

  P p;
  p.x       = (const float*)d_in[0];
  const float* Wr  = (const float*)d_in[1];
  const float* Wrb = (const float*)d_in[2];
  const float* Wi  = (const float*)d_in[3];
  const float* Wib = (const float*)d_in[4];
  const float* U   = (const float*)d_in[5];
  const float* Ub  = (const float*)d_in[6];
  const float* Wt  = (const float*)d_in[7];
  p.wtb     = (const float*)d_in[8];
  const float* mr  = (const float*)d_in[9];
  const float* mi  = (const float*)d_in[10];
  p.taubias = (const float*)d_in[11];
  const float* brl = (const float*)d_in[12];
  const float* bim = (const float*)d_in[13];
  const float* Ow  = (const float*)d_in[14];
  p.outb    = (const float*)d_in[15];

  p.tre_h = (u16*)alloc(Bn * Hn * 2);  p.tre_l = (u16*)alloc(Bn * Hn * 2);
  p.tim_h = (u16*)alloc(Bn * Hn * 2);  p.tim_l = (u16*)alloc(Bn * Hn * 2);
  p.zmod_h = (u16*)alloc(Bn * Hn * 2);
  p.zreh = (u16*)alloc(Bn * Hn * 2);   p.zrel = (u16*)alloc(Bn * Hn * 2);
  p.xh = (u16*)alloc(2 * Bn * INn * 2); p.xl = (u16*)alloc(2 * Bn * INn * 2);
  p.wr_h = (u16*)alloc(Hn * Hn * 2);   p.wr_l = (u16*)alloc(Hn * Hn * 2);
  p.wi_h = (u16*)alloc(Hn * Hn * 2);   p.wi_l = (u16*)alloc(Hn * Hn * 2);
  p.wt_h = (u16*)alloc(Hn * Hn * 2);   p.wt_l = (u16*)alloc(Hn * Hn * 2);
  p.uh = (u16*)alloc(Hn * INn * 2);    p.ul = (u16*)alloc(Hn * INn * 2);
  p.oh = (u16*)alloc(On * Hn * 2);     p.ol = (u16*)alloc(On * Hn * 2);
  p.bias_re = (float*)alloc(Hn * 4);   p.bias_im = (float*)alloc(Hn * 4);
  p.accL = (float*)alloc(Tn * 32 * 4);
  p.cntL = (int*)alloc(Tn * 32 * 4);
  p.accT = (float*)alloc(Tn * 4);
  p.cntT = (int*)alloc(Tn * 4);
  p.cnt2 = (int*)alloc(Tn * 8 * 4);
  p.barF = (int*)alloc(256);
  p.xcc  = (int*)alloc(NBLK * 4);
  p.out = (float*)d_out;

  prep_k<<<(Hn * Hn + NTH - 1) / NTH, NTH, 0, stream>>>(Wr, mr, Wi, mi, Wt, U, Ow,
                                                        Wrb, Ub, brl, Wib, bim, p);
  init_k<<<(Bn * Hn + NTH - 1) / NTH, NTH, 0, stream>>>(p);

  (void)hipFuncSetAttribute((const void*)twistor_k,
                            hipFuncAttributeMaxDynamicSharedMemorySize, DYN_BYTES);
  void* args[] = { &p };
  (void)hipLaunchCooperativeKernel((void*)twistor_k, dim3(NBLK), dim3(NT), args,
                                   DYN_BYTES, stream);
}

// Round 6
// 7219.203 us; speedup vs baseline: 8.9426x; 1.1876x over previous
//
#include <hip/hip_runtime.h>

// TwistorLNN persistent cooperative kernel, round 6.
// vs R5: counting-atomic barriers replaced with per-step write-once flag/value
// slots (poison-0xAA-safe) + distributed read-only polling. No atomic RMWs on
// hot lines, no counter resets, ~2 RTT per sync instead of contended spins.
//  - Norm: each block stores partial (>0) to partial[t][slot]; every block's
//    wave0 polls all 256 slots (reads pipeline), sums, computes scale locally.
//  - Publish: flag2[t][rg][cg]=1; consumers poll own rg's 32-word line.
//  - Fast path (rg-group XCD-colocated, runtime-verified): plain stores for
//    activations (stay in XCD L2), per-step L1-only buffer_inv.

namespace {

constexpr int Tn = 512, Bn = 256, INn = 256, Hn = 512, On = 64;
constexpr int NBLK = 256, NT = 512, NTH = 256;
constexpr float DTc = 0.1f, TAU_MINc = 0.01f, TAU_MAXc = 1.0f, DZDT_MAXc = 10.0f, Z_MAXc = 100.0f;

constexpr int LDH = 520;   // padded K-stride (u16), 16B-aligned rows
constexpr int LDI = 264;

constexpr int O_WRH = 0,     O_WRL = 8320,  O_WIH = 16640, O_WIL = 24960;
constexpr int O_WTH = 33280, O_WTL = 41600;
constexpr int O_UH  = 49920, O_UL  = 54144;
constexpr int O_OH  = 58368, O_OL  = 66688;
constexpr int DYN_BYTES = 75008 * 2;  // 150016

typedef short short8 __attribute__((ext_vector_type(8)));
typedef float f32x4 __attribute__((ext_vector_type(4)));
typedef unsigned short u16;
typedef unsigned int u32;

#define MFMA(a, b, c) __builtin_amdgcn_mfma_f32_16x16x32_bf16((a), (b), (c), 0, 0, 0)
#define AT_RLX __ATOMIC_RELAXED
#define SC_AGT __HIP_MEMORY_SCOPE_AGENT

struct P {
  const float *x, *wtb, *taubias, *outb;
  u16 *tre_h, *tre_l, *tim_h, *tim_l, *zmod_h, *zreh, *zrel;
  u16 *xh, *xl;             // double-buffered: [2][Bn*INn]
  u16 *wr_h, *wr_l, *wi_h, *wi_l, *wt_h, *wt_l, *uh, *ul, *oh, *ol;
  float *bias_re, *bias_im;
  float *partial;           // [Tn][256] block norm partials (>0); poison<0
  u32 *flag2;               // [Tn][8][32] publish flags (==1); poison!=1
  int *barF, *xcc;
  float *out;
};

__device__ __forceinline__ u16 f2bf(float f) {
  union { float f; unsigned u; } v; v.f = f;
  unsigned r = v.u + 0x7fffu + ((v.u >> 16) & 1u);
  return (u16)(r >> 16);
}
__device__ __forceinline__ float bf2f(u16 h) {
  union { unsigned u; float f; } v; v.u = ((unsigned)h) << 16;
  return v.f;
}
__device__ __forceinline__ void split_store(float v, u16* hi, u16* lo) {
  u16 h = f2bf(v); *hi = h; *lo = f2bf(v - bf2f(h));
}
__device__ __forceinline__ void split2(float v, u16& h, u16& l) {
  h = f2bf(v); l = f2bf(v - bf2f(h));
}
__device__ __forceinline__ u32 pk(u16 a, u16 b) { return (u32)a | ((u32)b << 16); }

__device__ __forceinline__ float fsig(float x) { return 1.f / (1.f + __expf(-x)); }
__device__ __forceinline__ float ftanh(float x) {
  float e = __expf(-2.f * fabsf(x));
  float t = (1.f - e) / (1.f + e);
  return copysignf(t, x);
}
__device__ __forceinline__ void l1_inv() {   // invalidate this CU's vector L1 only
  asm volatile("buffer_inv\n\ts_waitcnt vmcnt(0)" ::: "memory");
}

// ---------------- prep ----------------
__global__ void prep_k(const float* Wr, const float* mr, const float* Wi, const float* mi,
                       const float* Wt, const float* U, const float* Ow,
                       const float* Wrb, const float* Ub, const float* brl,
                       const float* Wib, const float* bim, P p) {
  int i = blockIdx.x * NTH + threadIdx.x;
  if (i < Hn * Hn) {
    float g = fsig(mr[i]);
    split_store(Wr[i] * g, &p.wr_h[i], &p.wr_l[i]);
    g = fsig(mi[i]);
    split_store(Wi[i] * g, &p.wi_h[i], &p.wi_l[i]);
    split_store(Wt[i], &p.wt_h[i], &p.wt_l[i]);
  }
  if (i < Hn * INn) split_store(U[i], &p.uh[i], &p.ul[i]);
  if (i < On * Hn)  split_store(Ow[i], &p.oh[i], &p.ol[i]);
  if (i < Hn) {
    p.bias_re[i] = Wrb[i] + Ub[i] + brl[i];
    p.bias_im[i] = Wib[i] + Ub[i] + bim[i];
  }
}

// ---------------- init ----------------
__global__ void init_k(P p) {
  int i = blockIdx.x * NTH + threadIdx.x;
  if (i < Bn * Hn) {
    p.tre_h[i] = 0; p.tre_l[i] = 0; p.tim_h[i] = 0; p.tim_l[i] = 0;
    p.zreh[i] = 0; p.zrel[i] = 0;
    p.zmod_h[i] = f2bf(1e-6f);
  }
  if (i < Bn * INn) split_store(p.x[i], &p.xh[i], &p.xl[i]);  // buffer 0
  if (i < 64) p.barF[i] = 0;
  // partial / flag2 need NO init: 0xAA poison is <0 (float) and !=1 (u32)
}

// ---------------- one-time full-fence grid barrier ----------------
__device__ void gbarF(int* bar) {
  __syncthreads();
  if (threadIdx.x == 0) {
    __threadfence();
    int g = __hip_atomic_load(bar + 32, AT_RLX, SC_AGT);
    int a = __hip_atomic_fetch_add(bar, 1, __ATOMIC_ACQ_REL, SC_AGT);
    if (a == NBLK - 1) {
      __hip_atomic_store(bar, 0, AT_RLX, SC_AGT);
      __hip_atomic_store(bar + 32, g + 1, __ATOMIC_RELEASE, SC_AGT);
    } else {
      while (__hip_atomic_load(bar + 32, __ATOMIC_ACQUIRE, SC_AGT) == g)
        __builtin_amdgcn_s_sleep(2);
    }
    __threadfence();
  }
  __syncthreads();
}

// ---------------- weight tile staging into LDS ----------------
template <int K, int LD>
__device__ __forceinline__ void stage(const u16* __restrict__ src, u16* dst, int grow0, int tid) {
  constexpr int CH = K / 8;
#pragma unroll
  for (int i = tid; i < 16 * CH; i += NT) {
    int n = i / CH, kk = (i % CH) * 8;
    *(short8*)(dst + n * LD + kk) = *(const short8*)(src + (size_t)(grow0 + n) * K + kk);
  }
}

// ---------------- 16x16 tile, A(h+l) global x B(h+l) LDS, bf16x3 ----------------
template <int K, int LDB>
__device__ __forceinline__ f32x4 mm1(const u16* __restrict__ ah, const u16* __restrict__ al,
                                     const u16* bh, const u16* bl,
                                     int arow0, int lda, int m, int q) {
  f32x4 acc = {0.f, 0.f, 0.f, 0.f};
  const u16* aph = ah + (size_t)(arow0 + m) * lda + q * 8;
  const u16* apl = al + (size_t)(arow0 + m) * lda + q * 8;
  const u16* bph = bh + m * LDB + q * 8;
  const u16* bpl = bl + m * LDB + q * 8;
#pragma unroll
  for (int k0 = 0; k0 < K; k0 += 32) {
    short8 Bh = *(const short8*)(bph + k0);
    short8 Bl = *(const short8*)(bpl + k0);
    short8 Ah = *(const short8*)(aph + k0);
    short8 Al = *(const short8*)(apl + k0);
    acc = MFMA(Ah, Bh, acc); acc = MFMA(Ah, Bl, acc); acc = MFMA(Al, Bh, acc);
  }
  return acc;
}

// A hi-only variant (tau path tolerates bf16 A)
template <int K, int LDB>
__device__ __forceinline__ f32x4 mm1h(const u16* __restrict__ ah,
                                      const u16* bh, const u16* bl,
                                      int arow0, int lda, int m, int q) {
  f32x4 acc = {0.f, 0.f, 0.f, 0.f};
  const u16* aph = ah + (size_t)(arow0 + m) * lda + q * 8;
  const u16* bph = bh + m * LDB + q * 8;
  const u16* bpl = bl + m * LDB + q * 8;
#pragma unroll
  for (int k0 = 0; k0 < K; k0 += 32) {
    short8 Bh = *(const short8*)(bph + k0);
    short8 Bl = *(const short8*)(bpl + k0);
    short8 Ah = *(const short8*)(aph + k0);
    acc = MFMA(Ah, Bh, acc); acc = MFMA(Ah, Bl, acc);
  }
  return acc;
}

__device__ __forceinline__ void yjob(const P& p, const u16* bh, const u16* bl,
                                     int rowbase, int ocol0, int ty, int m, int q) {
  f32x4 acc = mm1<Hn, LDH>(p.zreh, p.zrel, bh, bl, rowbase, Hn, m, q);
  int o = ocol0 + m;
  float ob = p.outb[o];
#pragma unroll
  for (int i = 0; i < 4; ++i)
    p.out[((size_t)ty * Bn + rowbase + q * 4 + i) * On + o] = acc[i] + ob;
}

// ---------------- persistent loop kernel ----------------
__global__ void __launch_bounds__(NT, 1) twistor_k(P p) {
  extern __shared__ __align__(16) u16 smem[];
  __shared__ float res[4][32][18];
  __shared__ float sb[4][16];
  __shared__ float wsum[8];
  __shared__ float sscale;
  __shared__ int sfast;

  const int bid = blockIdx.x, tid = threadIdx.x;
  const int rg = bid & 7, cg = bid >> 3;       // rg-group co-located per XCD (verified)
  const int wave = tid >> 6, lane = tid & 63, m = lane & 15, q = lane >> 4;
  const int row0 = rg * 32, col0 = cg * 16;
  const bool yblk = (cg >= 8 && cg < 16);
  const int yk = cg - 8;
  const int yrowbase = row0 + 16 * (yk & 1);
  const int yocol = (yk >> 1) * 16;

  stage<Hn, LDH>(p.wr_h, smem + O_WRH, col0, tid);
  stage<Hn, LDH>(p.wr_l, smem + O_WRL, col0, tid);
  stage<Hn, LDH>(p.wi_h, smem + O_WIH, col0, tid);
  stage<Hn, LDH>(p.wi_l, smem + O_WIL, col0, tid);
  stage<Hn, LDH>(p.wt_h, smem + O_WTH, col0, tid);
  stage<Hn, LDH>(p.wt_l, smem + O_WTL, col0, tid);
  stage<INn, LDI>(p.uh, smem + O_UH, col0, tid);
  stage<INn, LDI>(p.ul, smem + O_UL, col0, tid);
  int orow0 = yblk ? yocol : 0;
  stage<Hn, LDH>(p.oh, smem + O_OH, orow0, tid);
  stage<Hn, LDH>(p.ol, smem + O_OL, orow0, tid);
  if (tid < 16) {
    sb[0][tid] = p.bias_re[col0 + tid];
    sb[1][tid] = p.bias_im[col0 + tid];
    sb[2][tid] = p.wtb[col0 + tid];
    sb[3][tid] = p.taubias[col0 + tid];
  }

  // ---- runtime XCD-mapping check ----
  int xccid;
  asm volatile("s_getreg_b32 %0, hwreg(HW_REG_XCC_ID)" : "=s"(xccid));
  if (tid == 0) {
    __hip_atomic_store(&p.xcc[bid], xccid, AT_RLX, SC_AGT);
    sfast = 1;
  }
  gbarF(p.barF);
  if (tid < NBLK) {
    int v = __hip_atomic_load(&p.xcc[tid], AT_RLX, SC_AGT);
    int r = __hip_atomic_load(&p.xcc[tid & 7], AT_RLX, SC_AGT);
    if (v != r) atomicAnd(&sfast, 0);
  }
  __syncthreads();
  const bool fast = (sfast != 0);

  const int r = tid >> 4, c = tid & 15;
  const size_t idx = (size_t)(row0 + r) * Hn + col0 + c;
  const bool evenl = ((lane & 1) == 0);
  float zr = 0.f, zi = 0.f;

  for (int t = 0; t < Tn; ++t) {
    const u16* xh_r = p.xh + (size_t)(t & 1) * (Bn * INn);
    const u16* xl_r = p.xl + (size_t)(t & 1) * (Bn * INn);

    // prefetch next x row
    float xv = 0.f;
    if (tid < 256 && t + 1 < Tn)
      xv = p.x[(size_t)(t + 1) * (Bn * INn) + (size_t)(rg * 32 + cg) * INn + tid];

    // ===== phase A: MFMA jobs from published Z_t =====
    {
      const int job = wave >> 1, half = wave & 1;
      if (wave < 4) {
        const u16 *ah_ = (job == 0) ? p.tre_h : p.tim_h;
        const u16 *al_ = (job == 0) ? p.tre_l : p.tim_l;
        const u16 *bh_ = smem + ((job == 0) ? O_WRH : O_WIH);
        const u16 *bl_ = smem + ((job == 0) ? O_WRL : O_WIL);
        f32x4 a = mm1<Hn, LDH>(ah_, al_, bh_, bl_, row0 + 16 * half, Hn, m, q);
#pragma unroll
        for (int i = 0; i < 4; ++i) res[job][16 * half + q * 4 + i][m] = a[i];
      } else if (wave < 6) {
        f32x4 a = mm1h<Hn, LDH>(p.zmod_h, smem + O_WTH, smem + O_WTL,
                                row0 + 16 * half, Hn, m, q);
#pragma unroll
        for (int i = 0; i < 4; ++i) res[2][16 * half + q * 4 + i][m] = a[i];
      } else if (wave == 6) {
        f32x4 a = mm1<INn, LDI>(xh_r, xl_r, smem + O_UH, smem + O_UL, row0, INn, m, q);
#pragma unroll
        for (int i = 0; i < 4; ++i) res[3][q * 4 + i][m] = a[i];
        if (yblk) {
          f32x4 b = mm1<INn, LDI>(xh_r, xl_r, smem + O_UH, smem + O_UL, row0 + 16, INn, m, q);
#pragma unroll
          for (int i = 0; i < 4; ++i) res[3][16 + q * 4 + i][m] = b[i];
        }
      } else {
        if (!yblk) {
          f32x4 a = mm1<INn, LDI>(xh_r, xl_r, smem + O_UH, smem + O_UL, row0 + 16, INn, m, q);
#pragma unroll
          for (int i = 0; i < 4; ++i) res[3][16 + q * 4 + i][m] = a[i];
        } else if (t > 0) {
          yjob(p, smem + O_OH, smem + O_OL, yrowbase, yocol, t - 1, m, q);
        }
      }
    }

    // x-split store for t+1 (scale-independent; target buffer not read until t+1)
    if (tid < 256 && t + 1 < Tn) {
      u16 h, l; split2(xv, h, l);
      int nh = __shfl_down((int)h, 1, 64);
      int nl = __shfl_down((int)l, 1, 64);
      if (!(tid & 1)) {
        size_t xi = (size_t)((t + 1) & 1) * (Bn * INn) + (size_t)(rg * 32 + cg) * INn + tid;
        *(u32*)(p.xh + xi) = pk(h, (u16)nh);
        *(u32*)(p.xl + xi) = pk(l, (u16)nl);
      }
    }
    __syncthreads();

    // epilogue: dz, tau, d for own element
    float dr, di;
    {
      float ux = res[3][r][c];
      float dzre = -zr + res[0][r][c] + ux + sb[0][c];
      float dzim = -zi + res[1][r][c] + ux + sb[1][c];
      float tau = fsig(res[2][r][c] + sb[2][c]);
      tau = fminf(fmaxf(tau + sb[3][c], TAU_MINc), TAU_MAXc) + 1e-6f;
      float rt = 1.f / tau;
      dr = fminf(fmaxf(dzre * rt, -DZDT_MAXc), DZDT_MAXc);
      di = fminf(fmaxf(dzim * rt, -DZDT_MAXc), DZDT_MAXc);
    }
    float pn = sqrtf(dr * dr + di * di + 1e-12f);
#pragma unroll
    for (int off = 32; off > 0; off >>= 1) pn += __shfl_down(pn, off, 64);
    if (lane == 0) wsum[wave] = pn;
    __syncthreads();

    // ===== sync 1: store positive partial, poll all 256, compute scale locally =====
    if (tid == 0) {
      float s = 0.f;
#pragma unroll
      for (int w = 0; w < 8; ++w) s += wsum[w];
      __hip_atomic_store(&p.partial[(size_t)t * 256 + bid], s, AT_RLX, SC_AGT);
    }
    if (wave == 0) {
      const float* ps = p.partial + (size_t)t * 256;
      float s0, s1, s2, s3;
      for (;;) {
        s0 = __hip_atomic_load(ps + lane,       AT_RLX, SC_AGT);
        s1 = __hip_atomic_load(ps + lane + 64,  AT_RLX, SC_AGT);
        s2 = __hip_atomic_load(ps + lane + 128, AT_RLX, SC_AGT);
        s3 = __hip_atomic_load(ps + lane + 192, AT_RLX, SC_AGT);
        float mn = fminf(fminf(s0, s1), fminf(s2, s3));
#pragma unroll
        for (int o = 32; o > 0; o >>= 1) mn = fminf(mn, __shfl_xor(mn, o, 64));
        if (mn > 0.f) break;
        __builtin_amdgcn_s_sleep(1);
      }
      float sm = s0 + s1 + s2 + s3;
#pragma unroll
      for (int o = 32; o > 0; o >>= 1) sm += __shfl_xor(sm, o, 64);
      if (lane == 0) {
        float mean = sm * (1.f / (float)(Bn * Hn));
        sscale = (mean > 0.5f * DZDT_MAXc) ? (0.5f * DZDT_MAXc) / (mean + 1e-6f) : 1.f;
      }
    }
    __syncthreads();
    float scale = sscale;

    // ===== phase B: z update, publish Z_{t+1} with plain stores =====
    zr = fminf(fmaxf(zr + DTc * scale * dr, -Z_MAXc), Z_MAXc);
    zi = fminf(fmaxf(zi + DTc * scale * di, -Z_MAXc), Z_MAXc);
    {
      u16 h, l; int nh, nl;
      split2(ftanh(zr), h, l);
      nh = __shfl_down((int)h, 1, 64); nl = __shfl_down((int)l, 1, 64);
      if (evenl) { *(u32*)(p.tre_h + idx) = pk(h, (u16)nh); *(u32*)(p.tre_l + idx) = pk(l, (u16)nl); }
      split2(ftanh(zi), h, l);
      nh = __shfl_down((int)h, 1, 64); nl = __shfl_down((int)l, 1, 64);
      if (evenl) { *(u32*)(p.tim_h + idx) = pk(h, (u16)nh); *(u32*)(p.tim_l + idx) = pk(l, (u16)nl); }
      h = f2bf(sqrtf(zr * zr + zi * zi + 1e-12f));
      nh = __shfl_down((int)h, 1, 64);
      if (evenl) *(u32*)(p.zmod_h + idx) = pk(h, (u16)nh);
      split2(zr, h, l);
      nh = __shfl_down((int)h, 1, 64); nl = __shfl_down((int)l, 1, 64);
      if (evenl) { *(u32*)(p.zreh + idx) = pk(h, (u16)nh); *(u32*)(p.zrel + idx) = pk(l, (u16)nl); }
    }

    // ===== sync 2: publish flag + poll own rg's 32 flags =====
    __syncthreads();   // drains all waves' stores (vmcnt(0) before s_barrier)
    if (tid == 0) {
      if (!fast) __threadfence();   // slow path: write back L2 for cross-XCD consumers
      __hip_atomic_store(&p.flag2[(size_t)t * 256 + rg * 32 + cg], 1u, AT_RLX, SC_AGT);
    }
    if (wave == 0) {
      const u32* fs = p.flag2 + (size_t)t * 256 + rg * 32;
      for (;;) {
        u32 f = (lane < 32) ? __hip_atomic_load(fs + lane, AT_RLX, SC_AGT) : 1u;
        if (__ballot(f == 1u) == ~0ull) break;
        __builtin_amdgcn_s_sleep(1);
      }
    }
    __syncthreads();
    if (fast) l1_inv();                                      // L1-only invalidate
    else __builtin_amdgcn_fence(__ATOMIC_ACQUIRE, "agent");  // full (slow path)
  }

  if (yblk && wave == 7) yjob(p, smem + O_OH, smem + O_OL, yrowbase, yocol, Tn - 1, m, q);
}

}  // namespace

extern "C" void kernel_launch(void* const* d_in, const int* in_sizes, int n_in,
                              void* d_out, int out_size, void* d_ws, size_t ws_size,
                              hipStream_t stream) {
  (void)in_sizes; (void)n_in; (void)out_size; (void)ws_size;
  char* w = (char*)d_ws;
  auto alloc = [&](size_t bytes) -> char* {
    char* r = w; w += (bytes + 255) & ~(size_t)255; return r;
  };

  P p;
  p.x       = (const float*)d_in[0];
  const float* Wr  = (const float*)d_in[1];
  const float* Wrb = (const float*)d_in[2];
  const float* Wi  = (const float*)d_in[3];
  const float* Wib = (const float*)d_in[4];
  const float* U   = (const float*)d_in[5];
  const float* Ub  = (const float*)d_in[6];
  const float* Wt  = (const float*)d_in[7];
  p.wtb     = (const float*)d_in[8];
  const float* mr  = (const float*)d_in[9];
  const float* mi  = (const float*)d_in[10];
  p.taubias = (const float*)d_in[11];
  const float* brl = (const float*)d_in[12];
  const float* bim = (const float*)d_in[13];
  const float* Ow  = (const float*)d_in[14];
  p.outb    = (const float*)d_in[15];

  p.tre_h = (u16*)alloc(Bn * Hn * 2);  p.tre_l = (u16*)alloc(Bn * Hn * 2);
  p.tim_h = (u16*)alloc(Bn * Hn * 2);  p.tim_l = (u16*)alloc(Bn * Hn * 2);
  p.zmod_h = (u16*)alloc(Bn * Hn * 2);
  p.zreh = (u16*)alloc(Bn * Hn * 2);   p.zrel = (u16*)alloc(Bn * Hn * 2);
  p.xh = (u16*)alloc(2 * Bn * INn * 2); p.xl = (u16*)alloc(2 * Bn * INn * 2);
  p.wr_h = (u16*)alloc(Hn * Hn * 2);   p.wr_l = (u16*)alloc(Hn * Hn * 2);
  p.wi_h = (u16*)alloc(Hn * Hn * 2);   p.wi_l = (u16*)alloc(Hn * Hn * 2);
  p.wt_h = (u16*)alloc(Hn * Hn * 2);   p.wt_l = (u16*)alloc(Hn * Hn * 2);
  p.uh = (u16*)alloc(Hn * INn * 2);    p.ul = (u16*)alloc(Hn * INn * 2);
  p.oh = (u16*)alloc(On * Hn * 2);     p.ol = (u16*)alloc(On * Hn * 2);
  p.bias_re = (float*)alloc(Hn * 4);   p.bias_im = (float*)alloc(Hn * 4);
  p.partial = (float*)alloc((size_t)Tn * 256 * 4);
  p.flag2   = (u32*)alloc((size_t)Tn * 256 * 4);
  p.barF = (int*)alloc(256);
  p.xcc  = (int*)alloc(NBLK * 4);
  p.out = (float*)d_out;

  prep_k<<<(Hn * Hn + NTH - 1) / NTH, NTH, 0, stream>>>(Wr, mr, Wi, mi, Wt, U, Ow,
                                                        Wrb, Ub, brl, Wib, bim, p);
  init_k<<<(Bn * Hn + NTH - 1) / NTH, NTH, 0, stream>>>(p);

  (void)hipFuncSetAttribute((const void*)twistor_k,
                            hipFuncAttributeMaxDynamicSharedMemorySize, DYN_BYTES);
  void* args[] = { &p };
  (void)hipLaunchCooperativeKernel((void*)twistor_k, dim3(NBLK), dim3(NT), args,
                                   DYN_BYTES, stream);
}